// Round 1
// baseline (3046.489 us; speedup 1.0000x reference)
//
#include <hip/hip_runtime.h>
#include <hip/hip_bf16.h>
#include <cstddef>
#include <cstdint>

#define N_NODES 100000
#define N_EDGES 1600000
#define N_REL   4
#define N_BASES 30
#define FIN     86
#define HID     128
#define N_CLS   18
#define N_GRAPH 512

// W[r,i,o] = sum_b comp[r,b] * basis[b,i,o]
__global__ void k_wcomb(const float* __restrict__ basis, const float* __restrict__ comp,
                        float* __restrict__ W, int io_size, int total) {
    int i = blockIdx.x * 256 + threadIdx.x;
    if (i >= total) return;
    int r = i / io_size, io = i - r * io_size;
    float acc = 0.f;
#pragma unroll
    for (int b = 0; b < N_BASES; b++)
        acc += comp[r * N_BASES + b] * basis[(size_t)b * io_size + io];
    W[i] = acc;
}

// cnt[r*N + dst] += 1
__global__ void k_count(const int* __restrict__ et, const int* __restrict__ dst,
                        float* __restrict__ cnt) {
    int e = blockIdx.x * 256 + threadIdx.x;
    if (e >= N_EDGES) return;
    atomicAdd(cnt + (size_t)et[e] * N_NODES + dst[e], 1.0f);
}

// one wave per edge; if edge_type==rfilt, S[dst] += X[src]
template <int IN>
__global__ void k_agg(const int* __restrict__ et, const int* __restrict__ srcI,
                      const int* __restrict__ dstI, const float* __restrict__ X,
                      float* __restrict__ S, int rfilt) {
    int wave = (blockIdx.x * blockDim.x + threadIdx.x) >> 6;
    int lane = threadIdx.x & 63;
    if (wave >= N_EDGES) return;
    if (et[wave] != rfilt) return;
    const float* xp = X + (size_t)srcI[wave] * IN;
    float* sp = S + (size_t)dstI[wave] * IN;
#pragma unroll
    for (int f = lane; f < IN; f += 64) atomicAdd(sp + f, xp[f]);
}

// out[n, :] (MODE 0: =, 1: +=, 2: += then +bias, relu)  of  (A[n,:]* (1/max(cnt,1))) @ W
// W ([IN,128]) staged fully in LDS. 256 thr: 32 rows x 8 colgroups(16 cols each).
template <int IN, int MODE>
__launch_bounds__(256)
__global__ void k_gemm(const float* __restrict__ A, const float* __restrict__ cnt,
                       const float* __restrict__ W, const float* __restrict__ bias,
                       float* __restrict__ out) {
    __shared__ float sW[IN * HID];
    {
        const float4* w4 = reinterpret_cast<const float4*>(W);
        float4* s4 = reinterpret_cast<float4*>(sW);
        for (int i = threadIdx.x; i < IN * HID / 4; i += 256) s4[i] = w4[i];
    }
    __syncthreads();
    const int row = blockIdx.x * 32 + (threadIdx.x >> 3);
    const int c0 = (threadIdx.x & 7) * 16;
    float acc[16];
#pragma unroll
    for (int j = 0; j < 16; j++) acc[j] = 0.f;
    const float* a = A + (size_t)row * IN;
#pragma unroll 4
    for (int k = 0; k < IN; k++) {
        float av = a[k];
        const float* wr = &sW[k * HID + c0];
#pragma unroll
        for (int j = 0; j < 16; j++) acc[j] = fmaf(av, wr[j], acc[j]);
    }
    float s = 1.0f;
    if (cnt) s = 1.0f / fmaxf(cnt[row], 1.0f);
    float* o = out + (size_t)row * HID + c0;
    if (MODE == 0) {
#pragma unroll
        for (int j = 0; j < 16; j++) o[j] = acc[j] * s;
    } else if (MODE == 1) {
#pragma unroll
        for (int j = 0; j < 16; j++) o[j] += acc[j] * s;
    } else {
#pragma unroll
        for (int j = 0; j < 16; j++) {
            float v = o[j] + acc[j] * s + bias[c0 + j];
            o[j] = fmaxf(v, 0.f);
        }
    }
}

// g[batch[n]] += h2[n] + bias2  (bias2 folded: layer2 has no relu, pool is linear)
__global__ void k_pool(const float* __restrict__ h2, const float* __restrict__ bias2,
                       const int* __restrict__ batch, float* __restrict__ g) {
    int idx = blockIdx.x * 256 + threadIdx.x;
    int node = idx >> 5;
    if (node >= N_NODES) return;
    int c0 = (idx & 31) << 2;
    int b = batch[node];
    const float* hp = h2 + (size_t)node * HID + c0;
    float* gp = g + (size_t)b * HID + c0;
    atomicAdd(gp + 0, hp[0] + bias2[c0 + 0]);
    atomicAdd(gp + 1, hp[1] + bias2[c0 + 1]);
    atomicAdd(gp + 2, hp[2] + bias2[c0 + 2]);
    atomicAdd(gp + 3, hp[3] + bias2[c0 + 3]);
}

// per-graph: relu(g @ fc_w + fc_b) -> log_softmax
__global__ void k_fc(const float* __restrict__ g, const float* __restrict__ fcw,
                     const float* __restrict__ fcb, float* __restrict__ out) {
    __shared__ float vals[N_CLS];
    __shared__ float s_lse;
    int gi = blockIdx.x, t = threadIdx.x;
    if (t < N_CLS) {
        float acc = fcb[t];
        const float* gr = g + (size_t)gi * HID;
        for (int k = 0; k < HID; k++) acc = fmaf(gr[k], fcw[k * N_CLS + t], acc);
        vals[t] = fmaxf(acc, 0.f);
    }
    __syncthreads();
    if (t == 0) {
        float m = vals[0];
        for (int c = 1; c < N_CLS; c++) m = fmaxf(m, vals[c]);
        float ssum = 0.f;
        for (int c = 0; c < N_CLS; c++) ssum += expf(vals[c] - m);
        s_lse = m + logf(ssum);
    }
    __syncthreads();
    if (t < N_CLS) out[gi * N_CLS + t] = vals[t] - s_lse;
}

extern "C" void kernel_launch(void* const* d_in, const int* in_sizes, int n_in,
                              void* d_out, int out_size, void* d_ws, size_t ws_size,
                              hipStream_t stream) {
    const float* x      = (const float*)d_in[0];
    const int*   ei     = (const int*)d_in[1];
    const int*   src    = ei;
    const int*   dst    = ei + N_EDGES;
    const int*   et     = (const int*)d_in[2];
    const int*   batch  = (const int*)d_in[3];
    const float* basis1 = (const float*)d_in[4];
    const float* comp1  = (const float*)d_in[5];
    const float* root1  = (const float*)d_in[6];
    const float* bias1  = (const float*)d_in[7];
    const float* basis2 = (const float*)d_in[8];
    const float* comp2  = (const float*)d_in[9];
    const float* root2  = (const float*)d_in[10];
    const float* bias2  = (const float*)d_in[11];
    const float* fcw    = (const float*)d_in[12];
    const float* fcb    = (const float*)d_in[13];
    float* out = (float*)d_out;

    // workspace layout (floats). Peak ~156 MB.
    float* ws  = (float*)d_ws;
    float* W1  = ws;                       // 4*86*128   = 44032
    float* W2  = W1 + 4 * FIN * HID;       // 4*128*128  = 65536
    float* cnt = W2 + 4 * HID * HID;       // 400000
    float* h1  = cnt + N_REL * N_NODES;    // 12.8M
    float* h2  = h1 + (size_t)N_NODES * HID;
    float* S   = h2 + (size_t)N_NODES * HID;   // N*128 (reused per relation)
    float* g   = S + (size_t)N_NODES * HID;    // 512*128

    hipMemsetAsync(cnt, 0, (size_t)N_REL * N_NODES * sizeof(float), stream);
    hipMemsetAsync(g, 0, (size_t)N_GRAPH * HID * sizeof(float), stream);

    k_wcomb<<<(N_REL * FIN * HID + 255) / 256, 256, 0, stream>>>(basis1, comp1, W1, FIN * HID, N_REL * FIN * HID);
    k_wcomb<<<(N_REL * HID * HID + 255) / 256, 256, 0, stream>>>(basis2, comp2, W2, HID * HID, N_REL * HID * HID);
    k_count<<<(N_EDGES + 255) / 256, 256, 0, stream>>>(et, dst, cnt);

    const int GEMM_GRID = N_NODES / 32;            // 3125 (exact)
    const int AGG_GRID  = (N_EDGES * 64) / 256;    // one wave per edge

    // ---- layer 1: h1 = relu( sum_r mean_r(x)@W1_r + x@root1 + bias1 )
    k_gemm<FIN, 0><<<GEMM_GRID, 256, 0, stream>>>(x, nullptr, root1, nullptr, h1);
    for (int r = 0; r < N_REL; r++) {
        hipMemsetAsync(S, 0, (size_t)N_NODES * FIN * sizeof(float), stream);
        k_agg<FIN><<<AGG_GRID, 256, 0, stream>>>(et, src, dst, x, S, r);
        if (r < N_REL - 1)
            k_gemm<FIN, 1><<<GEMM_GRID, 256, 0, stream>>>(S, cnt + (size_t)r * N_NODES,
                                                          W1 + (size_t)r * FIN * HID, nullptr, h1);
        else
            k_gemm<FIN, 2><<<GEMM_GRID, 256, 0, stream>>>(S, cnt + (size_t)r * N_NODES,
                                                          W1 + (size_t)r * FIN * HID, bias1, h1);
    }

    // ---- layer 2: h2 = sum_r mean_r(h1)@W2_r + h1@root2   (bias2 folded into pool)
    k_gemm<HID, 0><<<GEMM_GRID, 256, 0, stream>>>(h1, nullptr, root2, nullptr, h2);
    for (int r = 0; r < N_REL; r++) {
        hipMemsetAsync(S, 0, (size_t)N_NODES * HID * sizeof(float), stream);
        k_agg<HID><<<AGG_GRID, 256, 0, stream>>>(et, src, dst, h1, S, r);
        k_gemm<HID, 1><<<GEMM_GRID, 256, 0, stream>>>(S, cnt + (size_t)r * N_NODES,
                                                      W2 + (size_t)r * HID * HID, nullptr, h2);
    }

    // ---- pool + fc + log_softmax
    k_pool<<<(N_NODES * 32 + 255) / 256, 256, 0, stream>>>(h2, bias2, batch, g);
    k_fc<<<N_GRAPH, 64, 0, stream>>>(g, fcw, fcb, out);
}

// Round 2
// 1681.367 us; speedup vs baseline: 1.8119x; 1.8119x over previous
//
#include <hip/hip_runtime.h>
#include <hip/hip_bf16.h>
#include <cstddef>
#include <cstdint>

#define N_NODES 100000
#define N_EDGES 1600000
#define N_REL   4
#define N_BASES 30
#define FIN     86
#define HID     128
#define N_CLS   18
#define N_GRAPH 512

#define SEG (N_REL * N_NODES)                         // 400000 segments
#define SCAN_CHUNK 1024
#define NB_SCAN ((SEG + SCAN_CHUNK - 1) / SCAN_CHUNK) // 391

// W[r,i,o] = sum_b comp[r,b] * basis[b,i,o]
__global__ void k_wcomb(const float* __restrict__ basis, const float* __restrict__ comp,
                        float* __restrict__ W, int io_size, int total) {
    int i = blockIdx.x * 256 + threadIdx.x;
    if (i >= total) return;
    int r = i / io_size, io = i - r * io_size;
    float acc = 0.f;
#pragma unroll
    for (int b = 0; b < N_BASES; b++)
        acc += comp[r * N_BASES + b] * basis[(size_t)b * io_size + io];
    W[i] = acc;
}

// cnt[r*N + dst] += 1  (int histogram, once per call)
__global__ void k_count(const int* __restrict__ et, const int* __restrict__ dst,
                        int* __restrict__ cnt) {
    int e = blockIdx.x * 256 + threadIdx.x;
    if (e >= N_EDGES) return;
    atomicAdd(cnt + et[e] * N_NODES + dst[e], 1);
}

// ---- 3-kernel exclusive scan of cnt[SEG] -> off[SEG] ----
__global__ void k_bsum(const int* __restrict__ cnt, int* __restrict__ bsum) {
    __shared__ int red[256];
    int base = blockIdx.x * SCAN_CHUNK + threadIdx.x * 4;
    int s = 0;
#pragma unroll
    for (int j = 0; j < 4; j++) { int idx = base + j; if (idx < SEG) s += cnt[idx]; }
    red[threadIdx.x] = s;
    __syncthreads();
    for (int w = 128; w > 0; w >>= 1) {
        if (threadIdx.x < w) red[threadIdx.x] += red[threadIdx.x + w];
        __syncthreads();
    }
    if (threadIdx.x == 0) bsum[blockIdx.x] = red[0];
}

__global__ void k_bpref(int* bsum, int nb) {  // in-place exclusive scan (tiny)
    if (threadIdx.x == 0 && blockIdx.x == 0) {
        int run = 0;
        for (int i = 0; i < nb; i++) { int t = bsum[i]; bsum[i] = run; run += t; }
    }
}

__global__ void k_offsets(const int* __restrict__ cnt, const int* __restrict__ bpref,
                          int* __restrict__ off) {
    __shared__ int tp[256];
    int t = threadIdx.x;
    int base = blockIdx.x * SCAN_CHUNK + t * 4;
    int v[4], s = 0;
#pragma unroll
    for (int j = 0; j < 4; j++) { int idx = base + j; v[j] = (idx < SEG) ? cnt[idx] : 0; s += v[j]; }
    tp[t] = s;
    __syncthreads();
    if (t == 0) { int run = 0; for (int i = 0; i < 256; i++) { int x = tp[i]; tp[i] = run; run += x; } }
    __syncthreads();
    int p = bpref[blockIdx.x] + tp[t];
#pragma unroll
    for (int j = 0; j < 4; j++) { int idx = base + j; if (idx < SEG) off[idx] = p; p += v[j]; }
}

// scatter edges into CSR order: ssrc[off[seg] + k] = src of k-th edge of segment
__global__ void k_scatter(const int* __restrict__ et, const int* __restrict__ srcI,
                          const int* __restrict__ dstI, const int* __restrict__ off,
                          int* __restrict__ cur, int* __restrict__ ssrc) {
    int e = blockIdx.x * 256 + threadIdx.x;
    if (e >= N_EDGES) return;
    int seg = et[e] * N_NODES + dstI[e];
    int pos = off[seg] + atomicAdd(cur + seg, 1);
    ssrc[pos] = srcI[e];
}

// one wave per node: S[n,:] = mean over segment (roff+n) of X[src,:]  (0 if empty)
template <int F>
__global__ void k_aggcsr(const int* __restrict__ off, const int* __restrict__ cnt,
                         const int* __restrict__ ssrc, const float* __restrict__ X,
                         float* __restrict__ S, int roff) {
    int wave = (blockIdx.x * 256 + threadIdx.x) >> 6;
    int lane = threadIdx.x & 63;
    if (wave >= N_NODES) return;
    int seg = roff + wave;
    int o0 = off[seg], c = cnt[seg];
    float a0 = 0.f, a1 = 0.f;
    for (int i = 0; i < c; i++) {
        const float* xp = X + (size_t)ssrc[o0 + i] * F;
        a0 += xp[lane];
        if (lane + 64 < F) a1 += xp[lane + 64];
    }
    float inv = (c > 0) ? (1.f / (float)c) : 0.f;
    float* sp = S + (size_t)wave * F;
    sp[lane] = a0 * inv;
    if (lane + 64 < F) sp[lane + 64] = a1 * inv;
}

// out[n,:] (MODE 0: =, 1: +=, 2: += then +bias, relu) of A[n,:] @ W
// W ([IN,128]) staged fully in LDS. 256 thr: 32 rows x 8 colgroups(16 cols).
template <int IN, int MODE>
__launch_bounds__(256)
__global__ void k_gemm(const float* __restrict__ A, const float* __restrict__ W,
                       const float* __restrict__ bias, float* __restrict__ out) {
    __shared__ float sW[IN * HID];
    {
        const float4* w4 = reinterpret_cast<const float4*>(W);
        float4* s4 = reinterpret_cast<float4*>(sW);
        for (int i = threadIdx.x; i < IN * HID / 4; i += 256) s4[i] = w4[i];
    }
    __syncthreads();
    const int row = blockIdx.x * 32 + (threadIdx.x >> 3);
    const int c0 = (threadIdx.x & 7) * 16;
    float acc[16];
#pragma unroll
    for (int j = 0; j < 16; j++) acc[j] = 0.f;
    const float* a = A + (size_t)row * IN;
#pragma unroll 4
    for (int k = 0; k < IN; k++) {
        float av = a[k];
        const float* wr = &sW[k * HID + c0];
#pragma unroll
        for (int j = 0; j < 16; j++) acc[j] = fmaf(av, wr[j], acc[j]);
    }
    float* o = out + (size_t)row * HID + c0;
    if (MODE == 0) {
#pragma unroll
        for (int j = 0; j < 16; j++) o[j] = acc[j];
    } else if (MODE == 1) {
#pragma unroll
        for (int j = 0; j < 16; j++) o[j] += acc[j];
    } else {
#pragma unroll
        for (int j = 0; j < 16; j++) {
            float v = o[j] + acc[j] + bias[c0 + j];
            o[j] = fmaxf(v, 0.f);
        }
    }
}

// segmented pool: batch sorted -> binary search graph bounds; 4 blocks/graph,
// register accumulate columns, one atomic per partial. bias2 folded (x count).
__global__ void k_pool(const float* __restrict__ h2, const float* __restrict__ bias2,
                       const int* __restrict__ batch, float* __restrict__ g) {
    __shared__ int s_lo, s_hi;
    int gi = blockIdx.x, q = blockIdx.y, t = threadIdx.x;
    if (t == 0) {
        int lo = 0, hi = N_NODES;
        while (lo < hi) { int m = (lo + hi) >> 1; if (batch[m] < gi) lo = m + 1; else hi = m; }
        s_lo = lo;
        int lo2 = lo, hi2 = N_NODES;
        while (lo2 < hi2) { int m = (lo2 + hi2) >> 1; if (batch[m] < gi + 1) lo2 = m + 1; else hi2 = m; }
        s_hi = lo2;
    }
    __syncthreads();
    int lo = s_lo, hi = s_hi;
    float acc = 0.f;
    for (int n = lo + q; n < hi; n += 4) acc += h2[(size_t)n * HID + t];
    if (q == 0) acc += (float)(hi - lo) * bias2[t];
    atomicAdd(&g[gi * HID + t], acc);
}

// per-graph: relu(g @ fc_w + fc_b) -> log_softmax
__global__ void k_fc(const float* __restrict__ g, const float* __restrict__ fcw,
                     const float* __restrict__ fcb, float* __restrict__ out) {
    __shared__ float vals[N_CLS];
    __shared__ float s_lse;
    int gi = blockIdx.x, t = threadIdx.x;
    if (t < N_CLS) {
        float acc = fcb[t];
        const float* gr = g + (size_t)gi * HID;
        for (int k = 0; k < HID; k++) acc = fmaf(gr[k], fcw[k * N_CLS + t], acc);
        vals[t] = fmaxf(acc, 0.f);
    }
    __syncthreads();
    if (t == 0) {
        float m = vals[0];
        for (int c = 1; c < N_CLS; c++) m = fmaxf(m, vals[c]);
        float ssum = 0.f;
        for (int c = 0; c < N_CLS; c++) ssum += expf(vals[c] - m);
        s_lse = m + logf(ssum);
    }
    __syncthreads();
    if (t < N_CLS) out[gi * N_CLS + t] = vals[t] - s_lse;
}

extern "C" void kernel_launch(void* const* d_in, const int* in_sizes, int n_in,
                              void* d_out, int out_size, void* d_ws, size_t ws_size,
                              hipStream_t stream) {
    const float* x      = (const float*)d_in[0];
    const int*   ei     = (const int*)d_in[1];
    const int*   src    = ei;
    const int*   dst    = ei + N_EDGES;
    const int*   et     = (const int*)d_in[2];
    const int*   batch  = (const int*)d_in[3];
    const float* basis1 = (const float*)d_in[4];
    const float* comp1  = (const float*)d_in[5];
    const float* root1  = (const float*)d_in[6];
    const float* bias1  = (const float*)d_in[7];
    const float* basis2 = (const float*)d_in[8];
    const float* comp2  = (const float*)d_in[9];
    const float* root2  = (const float*)d_in[10];
    const float* bias2  = (const float*)d_in[11];
    const float* fcw    = (const float*)d_in[12];
    const float* fcb    = (const float*)d_in[13];
    float* out = (float*)d_out;

    // workspace layout. ~166 MB total.
    float* ws   = (float*)d_ws;
    float* W1   = ws;                               // 4*86*128  = 44032
    float* W2   = W1 + N_REL * FIN * HID;           // 4*128*128 = 65536
    float* g    = W2 + N_REL * HID * HID;           // 512*128
    float* h1   = g + N_GRAPH * HID;                // 12.8M
    float* h2   = h1 + (size_t)N_NODES * HID;       // 12.8M
    float* S    = h2 + (size_t)N_NODES * HID;       // 12.8M (reused per relation)
    int*   cnt  = (int*)(S + (size_t)N_NODES * HID);// 400000
    int*   off  = cnt + SEG;                        // 400000
    int*   cur  = off + SEG;                        // 400000
    int*   bsum = cur + SEG;                        // 512
    int*   ssrc = bsum + 512;                       // 1.6M

    hipMemsetAsync(cnt, 0, SEG * sizeof(int), stream);
    hipMemsetAsync(cur, 0, SEG * sizeof(int), stream);
    hipMemsetAsync(g, 0, (size_t)N_GRAPH * HID * sizeof(float), stream);

    k_wcomb<<<(N_REL * FIN * HID + 255) / 256, 256, 0, stream>>>(basis1, comp1, W1, FIN * HID, N_REL * FIN * HID);
    k_wcomb<<<(N_REL * HID * HID + 255) / 256, 256, 0, stream>>>(basis2, comp2, W2, HID * HID, N_REL * HID * HID);

    // ---- build CSR by (relation, dst): count -> scan -> scatter
    k_count<<<(N_EDGES + 255) / 256, 256, 0, stream>>>(et, dst, cnt);
    k_bsum<<<NB_SCAN, 256, 0, stream>>>(cnt, bsum);
    k_bpref<<<1, 64, 0, stream>>>(bsum, NB_SCAN);
    k_offsets<<<NB_SCAN, 256, 0, stream>>>(cnt, bsum, off);
    k_scatter<<<(N_EDGES + 255) / 256, 256, 0, stream>>>(et, src, dst, off, cur, ssrc);

    const int GEMM_GRID = N_NODES / 32;             // 3125 (exact)
    const int AGG_GRID  = (N_NODES * 64 + 255) / 256;

    // ---- layer 1: h1 = relu( sum_r mean_r(x)@W1_r + x@root1 + bias1 )
    k_gemm<FIN, 0><<<GEMM_GRID, 256, 0, stream>>>(x, root1, nullptr, h1);
    for (int r = 0; r < N_REL; r++) {
        k_aggcsr<FIN><<<AGG_GRID, 256, 0, stream>>>(off, cnt, ssrc, x, S, r * N_NODES);
        if (r < N_REL - 1)
            k_gemm<FIN, 1><<<GEMM_GRID, 256, 0, stream>>>(S, W1 + (size_t)r * FIN * HID, nullptr, h1);
        else
            k_gemm<FIN, 2><<<GEMM_GRID, 256, 0, stream>>>(S, W1 + (size_t)r * FIN * HID, bias1, h1);
    }

    // ---- layer 2: h2 = sum_r mean_r(h1)@W2_r + h1@root2  (bias2 folded into pool)
    k_gemm<HID, 0><<<GEMM_GRID, 256, 0, stream>>>(h1, root2, nullptr, h2);
    for (int r = 0; r < N_REL; r++) {
        k_aggcsr<HID><<<AGG_GRID, 256, 0, stream>>>(off, cnt, ssrc, h1, S, r * N_NODES);
        k_gemm<HID, 1><<<GEMM_GRID, 256, 0, stream>>>(S, W2 + (size_t)r * HID * HID, nullptr, h2);
    }

    // ---- pool + fc + log_softmax
    k_pool<<<dim3(N_GRAPH, 4), HID, 0, stream>>>(h2, bias2, batch, g);
    k_fc<<<N_GRAPH, 64, 0, stream>>>(g, fcw, fcb, out);
}

// Round 3
// 812.706 us; speedup vs baseline: 3.7486x; 2.0689x over previous
//
#include <hip/hip_runtime.h>
#include <hip/hip_bf16.h>
#include <cstddef>
#include <cstdint>

#define N_NODES 100000
#define N_ROWS  100032            // padded to 64-row blocks
#define N_EDGES 1600000
#define N_REL   4
#define N_BASES 30
#define FIN     86
#define HID     128
#define N_CLS   18
#define N_GRAPH 512
#define KCAT    640               // 4 relation blocks + root block, 128 each

#define SEG (N_REL * N_NODES)                         // 400000 segments
#define SCAN_CHUNK 1024
#define NB_SCAN ((SEG + SCAN_CHUNK - 1) / SCAN_CHUNK) // 391

typedef __attribute__((ext_vector_type(8))) short bf16x8;
typedef __attribute__((ext_vector_type(4))) float f32x4;

__device__ inline float bf2f(unsigned short u) {
    union { unsigned int i; float f; } c; c.i = ((unsigned int)u) << 16; return c.f;
}
__device__ inline unsigned short f2bf(float f) {
    __hip_bfloat16 h = __float2bfloat16(f);
    return *reinterpret_cast<unsigned short*>(&h);
}

// Stacked transposed weights: Wt[n][s], s = r*128+k (r<4: sum_b comp*basis) or 512+k (root).
// Zero-padded for k >= KV.
template <int KV>
__global__ void k_wt(const float* __restrict__ basis, const float* __restrict__ comp,
                     const float* __restrict__ root, short* __restrict__ Wt) {
    int id = blockIdx.x * 256 + threadIdx.x;      // over KCAT*HID, n fastest (coalesced)
    if (id >= KCAT * HID) return;
    int n = id & 127, s = id >> 7;
    int k = s & 127, blk = s >> 7;
    float v = 0.f;
    if (k < KV) {
        if (blk < N_REL) {
#pragma unroll
            for (int b = 0; b < N_BASES; ++b)
                v += comp[blk * N_BASES + b] * basis[((size_t)b * KV + k) * HID + n];
        } else {
            v = root[k * HID + n];
        }
    }
    Wt[(size_t)n * KCAT + s] = (short)f2bf(v);
}

// x[N,86] f32 -> CS[:, 512..639] bf16 (zero pad k>=86)
__global__ void k_xcvt(const float* __restrict__ x, short* __restrict__ CS) {
    int id = blockIdx.x * 256 + threadIdx.x;
    if (id >= N_NODES * HID) return;
    int n = id >> 7, k = id & 127;
    float v = (k < FIN) ? x[n * FIN + k] : 0.f;
    CS[(size_t)n * KCAT + 512 + k] = (short)f2bf(v);
}

// cnt[r*N + dst] += 1
__global__ void k_count(const int* __restrict__ et, const int* __restrict__ dst,
                        int* __restrict__ cnt) {
    int e = blockIdx.x * 256 + threadIdx.x;
    if (e >= N_EDGES) return;
    atomicAdd(cnt + et[e] * N_NODES + dst[e], 1);
}

// ---- 3-kernel exclusive scan of cnt[SEG] -> off[SEG] ----
__global__ void k_bsum(const int* __restrict__ cnt, int* __restrict__ bsum) {
    __shared__ int red[256];
    int base = blockIdx.x * SCAN_CHUNK + threadIdx.x * 4;
    int s = 0;
#pragma unroll
    for (int j = 0; j < 4; j++) { int idx = base + j; if (idx < SEG) s += cnt[idx]; }
    red[threadIdx.x] = s;
    __syncthreads();
    for (int w = 128; w > 0; w >>= 1) {
        if (threadIdx.x < w) red[threadIdx.x] += red[threadIdx.x + w];
        __syncthreads();
    }
    if (threadIdx.x == 0) bsum[blockIdx.x] = red[0];
}

__global__ void k_bpref(int* bsum, int nb) {
    if (threadIdx.x == 0 && blockIdx.x == 0) {
        int run = 0;
        for (int i = 0; i < nb; i++) { int t = bsum[i]; bsum[i] = run; run += t; }
    }
}

__global__ void k_offsets(const int* __restrict__ cnt, const int* __restrict__ bpref,
                          int* __restrict__ off) {
    __shared__ int tp[256];
    int t = threadIdx.x;
    int base = blockIdx.x * SCAN_CHUNK + t * 4;
    int v[4], s = 0;
#pragma unroll
    for (int j = 0; j < 4; j++) { int idx = base + j; v[j] = (idx < SEG) ? cnt[idx] : 0; s += v[j]; }
    tp[t] = s;
    __syncthreads();
    if (t == 0) { int run = 0; for (int i = 0; i < 256; i++) { int x = tp[i]; tp[i] = run; run += x; } }
    __syncthreads();
    int p = bpref[blockIdx.x] + tp[t];
#pragma unroll
    for (int j = 0; j < 4; j++) { int idx = base + j; if (idx < SEG) off[idx] = p; p += v[j]; }
}

__global__ void k_scatter(const int* __restrict__ et, const int* __restrict__ srcI,
                          const int* __restrict__ dstI, const int* __restrict__ off,
                          int* __restrict__ cur, int* __restrict__ ssrc) {
    int e = blockIdx.x * 256 + threadIdx.x;
    if (e >= N_EDGES) return;
    int seg = et[e] * N_NODES + dstI[e];
    int pos = off[seg] + atomicAdd(cur + seg, 1);
    ssrc[pos] = srcI[e];
}

// one wave per node: for each relation r, CS[node][r*128+k] = mean over segment of
// CS[src][512+k] (the current feature block). Reads (cols 512..639) and writes
// (cols 0..511) are disjoint -> no intra-kernel hazard.
__global__ void k_agg2(const int* __restrict__ off, const int* __restrict__ cnt,
                       const int* __restrict__ ssrc, short* __restrict__ CS) {
    int node = (blockIdx.x * 256 + threadIdx.x) >> 6;
    int lane = threadIdx.x & 63;
    if (node >= N_NODES) return;
    const int k2 = lane * 2;
#pragma unroll
    for (int r = 0; r < N_REL; ++r) {
        int seg = r * N_NODES + node;
        int o0 = off[seg], c = cnt[seg];
        float a0 = 0.f, a1 = 0.f;
        for (int i = 0; i < c; ++i) {
            int row = ssrc[o0 + i];
            unsigned int v = *reinterpret_cast<const unsigned int*>(
                CS + (size_t)row * KCAT + 512 + k2);
            a0 += bf2f((unsigned short)(v & 0xffffu));
            a1 += bf2f((unsigned short)(v >> 16));
        }
        float inv = (c > 0) ? 1.f / (float)c : 0.f;
        unsigned int w = (unsigned int)f2bf(a0 * inv) | ((unsigned int)f2bf(a1 * inv) << 16);
        *reinterpret_cast<unsigned int*>(CS + (size_t)node * KCAT + r * HID + k2) = w;
    }
}

// MFMA GEMM: out[M=100032 pad][128] = A(CS)[M][640] @ W[640][128], via Wt[128][640].
// Block: 64 rows x 128 cols, 4 waves; wave w covers all 64 rows x cols [32w,32w+32).
// MODE 1: relu(.+bias) -> bf16 into CS[:,512..639] (h1).  MODE 2: bf16 -> h2b[M][128].
// mfma_f32_16x16x32_bf16 layouts: A lane: row=l&15, k=(l>>4)*8+j; B lane: col=l&15,
// k=(l>>4)*8+j; D lane: col=l&15, row=(l>>4)*4+reg.
template <int MODE>
__launch_bounds__(256)
__global__ void k_gemm(const short* __restrict__ A, const short* __restrict__ Wt,
                       const float* __restrict__ bias, short* __restrict__ outb) {
    const int wave = threadIdx.x >> 6, lane = threadIdx.x & 63;
    const int m0 = blockIdx.x * 64;
    const int col0 = wave * 32;
    const int q = lane & 15;
    const int kq = (lane >> 4) * 8;
    const short* ap = A + (size_t)(m0 + q) * KCAT + kq;
    const short* bp = Wt + (size_t)(col0 + q) * KCAT + kq;
    f32x4 acc[4][2];
#pragma unroll
    for (int i = 0; i < 4; i++)
#pragma unroll
        for (int j = 0; j < 2; j++) acc[i][j] = (f32x4){0.f, 0.f, 0.f, 0.f};
    for (int kk = 0; kk < KCAT / 32; ++kk) {
        const int ko = kk * 32;
        bf16x8 b0 = *reinterpret_cast<const bf16x8*>(bp + ko);
        bf16x8 b1 = *reinterpret_cast<const bf16x8*>(bp + (size_t)16 * KCAT + ko);
#pragma unroll
        for (int rf = 0; rf < 4; ++rf) {
            bf16x8 a = *reinterpret_cast<const bf16x8*>(ap + (size_t)rf * 16 * KCAT + ko);
            acc[rf][0] = __builtin_amdgcn_mfma_f32_16x16x32_bf16(a, b0, acc[rf][0], 0, 0, 0);
            acc[rf][1] = __builtin_amdgcn_mfma_f32_16x16x32_bf16(a, b1, acc[rf][1], 0, 0, 0);
        }
    }
    const int rq = (lane >> 4) * 4;
#pragma unroll
    for (int rf = 0; rf < 4; ++rf) {
#pragma unroll
        for (int cf = 0; cf < 2; ++cf) {
            const int col = col0 + cf * 16 + q;
#pragma unroll
            for (int r = 0; r < 4; ++r) {
                const int row = m0 + rf * 16 + rq + r;
                if (row < N_NODES) {
                    float v = acc[rf][cf][r];
                    if (MODE == 1) {
                        v = fmaxf(v + bias[col], 0.f);
                        outb[(size_t)row * KCAT + 512 + col] = (short)f2bf(v);
                    } else {
                        outb[(size_t)row * HID + col] = (short)f2bf(v);
                    }
                }
            }
        }
    }
}

// segmented pool over sorted batch; 4 blocks/graph; bias2 folded (x node count)
__global__ void k_pool(const short* __restrict__ h2b, const float* __restrict__ bias2,
                       const int* __restrict__ batch, float* __restrict__ g) {
    __shared__ int s_lo, s_hi;
    int gi = blockIdx.x, qb = blockIdx.y, t = threadIdx.x;
    if (t == 0) {
        int lo = 0, hi = N_NODES;
        while (lo < hi) { int m = (lo + hi) >> 1; if (batch[m] < gi) lo = m + 1; else hi = m; }
        s_lo = lo;
        int lo2 = lo, hi2 = N_NODES;
        while (lo2 < hi2) { int m = (lo2 + hi2) >> 1; if (batch[m] < gi + 1) lo2 = m + 1; else hi2 = m; }
        s_hi = lo2;
    }
    __syncthreads();
    int lo = s_lo, hi = s_hi;
    float acc = 0.f;
    for (int n = lo + qb; n < hi; n += 4)
        acc += bf2f((unsigned short)h2b[(size_t)n * HID + t]);
    if (qb == 0) acc += (float)(hi - lo) * bias2[t];
    atomicAdd(&g[gi * HID + t], acc);
}

// per-graph: relu(g @ fc_w + fc_b) -> log_softmax
__global__ void k_fc(const float* __restrict__ g, const float* __restrict__ fcw,
                     const float* __restrict__ fcb, float* __restrict__ out) {
    __shared__ float vals[N_CLS];
    __shared__ float s_lse;
    int gi = blockIdx.x, t = threadIdx.x;
    if (t < N_CLS) {
        float acc = fcb[t];
        const float* gr = g + (size_t)gi * HID;
        for (int k = 0; k < HID; k++) acc = fmaf(gr[k], fcw[k * N_CLS + t], acc);
        vals[t] = fmaxf(acc, 0.f);
    }
    __syncthreads();
    if (t == 0) {
        float m = vals[0];
        for (int c = 1; c < N_CLS; c++) m = fmaxf(m, vals[c]);
        float ssum = 0.f;
        for (int c = 0; c < N_CLS; c++) ssum += expf(vals[c] - m);
        s_lse = m + logf(ssum);
    }
    __syncthreads();
    if (t < N_CLS) out[gi * N_CLS + t] = vals[t] - s_lse;
}

extern "C" void kernel_launch(void* const* d_in, const int* in_sizes, int n_in,
                              void* d_out, int out_size, void* d_ws, size_t ws_size,
                              hipStream_t stream) {
    const float* x      = (const float*)d_in[0];
    const int*   ei     = (const int*)d_in[1];
    const int*   src    = ei;
    const int*   dst    = ei + N_EDGES;
    const int*   et     = (const int*)d_in[2];
    const int*   batch  = (const int*)d_in[3];
    const float* basis1 = (const float*)d_in[4];
    const float* comp1  = (const float*)d_in[5];
    const float* root1  = (const float*)d_in[6];
    const float* bias1  = (const float*)d_in[7];
    const float* basis2 = (const float*)d_in[8];
    const float* comp2  = (const float*)d_in[9];
    const float* root2  = (const float*)d_in[10];
    const float* bias2  = (const float*)d_in[11];
    const float* fcw    = (const float*)d_in[12];
    const float* fcb    = (const float*)d_in[13];
    float* out = (float*)d_out;

    // workspace layout (~165.4 MB, within round-2's proven footprint)
    short* CS   = (short*)d_ws;                        // [100032][640] bf16  = 128.04 MB
    short* h2b  = CS + (size_t)N_ROWS * KCAT;          // [100000][128] bf16  = 25.6 MB
    short* Wt1  = h2b + (size_t)N_NODES * HID;         // [128][640] bf16
    short* Wt2  = Wt1 + HID * KCAT;                    // [128][640] bf16
    float* g    = (float*)(Wt2 + HID * KCAT);          // [512][128] f32
    int*   cnt  = (int*)(g + N_GRAPH * HID);           // SEG
    int*   off  = cnt + SEG;
    int*   cur  = off + SEG;
    int*   bsum = cur + SEG;                           // 512
    int*   ssrc = bsum + 512;                          // E

    hipMemsetAsync(cnt, 0, SEG * sizeof(int), stream);
    hipMemsetAsync(cur, 0, SEG * sizeof(int), stream);
    hipMemsetAsync(g, 0, (size_t)N_GRAPH * HID * sizeof(float), stream);

    k_wt<FIN><<<(KCAT * HID + 255) / 256, 256, 0, stream>>>(basis1, comp1, root1, Wt1);
    k_wt<HID><<<(KCAT * HID + 255) / 256, 256, 0, stream>>>(basis2, comp2, root2, Wt2);
    k_xcvt<<<(N_NODES * HID + 255) / 256, 256, 0, stream>>>(x, CS);

    // CSR build by (relation, dst)
    k_count<<<(N_EDGES + 255) / 256, 256, 0, stream>>>(et, dst, cnt);
    k_bsum<<<NB_SCAN, 256, 0, stream>>>(cnt, bsum);
    k_bpref<<<1, 64, 0, stream>>>(bsum, NB_SCAN);
    k_offsets<<<NB_SCAN, 256, 0, stream>>>(cnt, bsum, off);
    k_scatter<<<(N_EDGES + 255) / 256, 256, 0, stream>>>(et, src, dst, off, cur, ssrc);

    const int AGG_GRID  = N_NODES / 4;     // 1 wave/node, 4 waves/block
    const int GEMM_GRID = N_ROWS / 64;     // 1563

    // layer 1: agg means of x into CS[:,0..511]; h1 = relu(CS @ W1stack + bias1) -> CS[:,512..639]
    k_agg2<<<AGG_GRID, 256, 0, stream>>>(off, cnt, ssrc, CS);
    k_gemm<1><<<GEMM_GRID, 256, 0, stream>>>(CS, Wt1, bias1, CS);

    // layer 2: agg means of h1; h2 = CS @ W2stack -> h2b (bias2 folded into pool)
    k_agg2<<<AGG_GRID, 256, 0, stream>>>(off, cnt, ssrc, CS);
    k_gemm<2><<<GEMM_GRID, 256, 0, stream>>>(CS, Wt2, nullptr, h2b);

    // pool + fc + log_softmax
    k_pool<<<dim3(N_GRAPH, 4), HID, 0, stream>>>(h2b, bias2, batch, g);
    k_fc<<<N_GRAPH, 64, 0, stream>>>(g, fcw, fcb, out);
}

// Round 4
// 620.937 us; speedup vs baseline: 4.9063x; 1.3088x over previous
//
#include <hip/hip_runtime.h>
#include <hip/hip_bf16.h>
#include <cstddef>
#include <cstdint>

#define N_NODES 100000
#define N_ROWS  100032            // padded to 64-row blocks
#define N_EDGES 1600000
#define N_REL   4
#define N_BASES 30
#define FIN     86
#define HID     128
#define N_CLS   18
#define N_GRAPH 512
#define KCAT    640               // 4 relation blocks + root block, 128 each

#define SEG (N_REL * N_NODES)                         // 400000 segments
#define SCAN_CHUNK 1024
#define NB_SCAN ((SEG + SCAN_CHUNK - 1) / SCAN_CHUNK) // 391

typedef __attribute__((ext_vector_type(8))) short bf16x8;
typedef __attribute__((ext_vector_type(4))) float f32x4;

__device__ inline float bf2f(unsigned int u16) {
    union { unsigned int i; float f; } c; c.i = u16 << 16; return c.f;
}
__device__ inline unsigned short f2bf(float f) {
    __hip_bfloat16 h = __float2bfloat16(f);
    return *reinterpret_cast<unsigned short*>(&h);
}
__device__ inline unsigned int pk2(float lo, float hi) {
    return (unsigned int)f2bf(lo) | ((unsigned int)f2bf(hi) << 16);
}

// Stacked transposed weights: Wt[n][s], s = r*128+k (r<4: sum_b comp*basis) or 512+k (root).
template <int KV>
__global__ void k_wt(const float* __restrict__ basis, const float* __restrict__ comp,
                     const float* __restrict__ root, short* __restrict__ Wt) {
    int id = blockIdx.x * 256 + threadIdx.x;
    if (id >= KCAT * HID) return;
    int n = id & 127, s = id >> 7;
    int k = s & 127, blk = s >> 7;
    float v = 0.f;
    if (k < KV) {
        if (blk < N_REL) {
#pragma unroll
            for (int b = 0; b < N_BASES; ++b)
                v += comp[blk * N_BASES + b] * basis[((size_t)b * KV + k) * HID + n];
        } else {
            v = root[k * HID + n];
        }
    }
    Wt[(size_t)n * KCAT + s] = (short)f2bf(v);
}

// x[N,86] f32 -> CS[:, 512..639] bf16 (zero pad k>=86)
__global__ void k_xcvt(const float* __restrict__ x, short* __restrict__ CS) {
    int id = blockIdx.x * 256 + threadIdx.x;
    if (id >= N_NODES * HID) return;
    int n = id >> 7, k = id & 127;
    float v = (k < FIN) ? x[n * FIN + k] : 0.f;
    CS[(size_t)n * KCAT + 512 + k] = (short)f2bf(v);
}

// histogram + per-edge rank in one atomic pass
__global__ void k_count(const int* __restrict__ et, const int* __restrict__ dst,
                        int* __restrict__ cnt, int* __restrict__ rank) {
    int e = blockIdx.x * 256 + threadIdx.x;
    if (e >= N_EDGES) return;
    rank[e] = atomicAdd(cnt + et[e] * N_NODES + dst[e], 1);
}

// ---- 3-kernel exclusive scan of cnt[SEG] -> off[SEG] ----
__global__ void k_bsum(const int* __restrict__ cnt, int* __restrict__ bsum) {
    __shared__ int red[256];
    int base = blockIdx.x * SCAN_CHUNK + threadIdx.x * 4;
    int s = 0;
#pragma unroll
    for (int j = 0; j < 4; j++) { int idx = base + j; if (idx < SEG) s += cnt[idx]; }
    red[threadIdx.x] = s;
    __syncthreads();
    for (int w = 128; w > 0; w >>= 1) {
        if (threadIdx.x < w) red[threadIdx.x] += red[threadIdx.x + w];
        __syncthreads();
    }
    if (threadIdx.x == 0) bsum[blockIdx.x] = red[0];
}

__global__ void k_bpref(int* bsum, int nb) {
    if (threadIdx.x == 0 && blockIdx.x == 0) {
        int run = 0;
        for (int i = 0; i < nb; i++) { int t = bsum[i]; bsum[i] = run; run += t; }
    }
}

__global__ void k_offsets(const int* __restrict__ cnt, const int* __restrict__ bpref,
                          int* __restrict__ off) {
    __shared__ int tp[256];
    int t = threadIdx.x;
    int base = blockIdx.x * SCAN_CHUNK + t * 4;
    int v[4], s = 0;
#pragma unroll
    for (int j = 0; j < 4; j++) { int idx = base + j; v[j] = (idx < SEG) ? cnt[idx] : 0; s += v[j]; }
    tp[t] = s;
    __syncthreads();
    if (t == 0) { int run = 0; for (int i = 0; i < 256; i++) { int x = tp[i]; tp[i] = run; run += x; } }
    __syncthreads();
    int p = bpref[blockIdx.x] + tp[t];
#pragma unroll
    for (int j = 0; j < 4; j++) { int idx = base + j; if (idx < SEG) off[idx] = p; p += v[j]; }
}

// atomic-free scatter using precomputed rank
__global__ void k_scatter(const int* __restrict__ et, const int* __restrict__ srcI,
                          const int* __restrict__ dstI, const int* __restrict__ off,
                          const int* __restrict__ rank, int* __restrict__ ssrc) {
    int e = blockIdx.x * 256 + threadIdx.x;
    if (e >= N_EDGES) return;
    int seg = et[e] * N_NODES + dstI[e];
    ssrc[off[seg] + rank[e]] = srcI[e];
}

// one wave per node; 4 groups x 16 lanes: group g gathers neighbor (i+g)'s row as
// uint4 (8 bf16/lane -> full 256B row per group). Butterfly-reduce across groups,
// lanes 0..15 write the packed mean (16B). 4 independent gather chains per trip.
__global__ void k_agg2(const int* __restrict__ off, const int* __restrict__ cnt,
                       const int* __restrict__ ssrc, short* __restrict__ CS) {
    int node = (blockIdx.x * 256 + threadIdx.x) >> 6;
    int lane = threadIdx.x & 63;
    if (node >= N_NODES) return;
    const int g = lane >> 4, q = lane & 15;
    const int colb = q * 8;
    const size_t obase = (size_t)node * KCAT;
#pragma unroll
    for (int r = 0; r < N_REL; ++r) {
        int seg = r * N_NODES + node;
        int o0 = off[seg], c = cnt[seg];
        float a[8];
#pragma unroll
        for (int j = 0; j < 8; j++) a[j] = 0.f;
        for (int i = g; i < c; i += 4) {
            int row = ssrc[o0 + i];
            uint4 v = *reinterpret_cast<const uint4*>(CS + (size_t)row * KCAT + 512 + colb);
            a[0] += bf2f(v.x & 0xffffu); a[1] += bf2f(v.x >> 16);
            a[2] += bf2f(v.y & 0xffffu); a[3] += bf2f(v.y >> 16);
            a[4] += bf2f(v.z & 0xffffu); a[5] += bf2f(v.z >> 16);
            a[6] += bf2f(v.w & 0xffffu); a[7] += bf2f(v.w >> 16);
        }
#pragma unroll
        for (int j = 0; j < 8; j++) {
            a[j] += __shfl_xor(a[j], 16, 64);
            a[j] += __shfl_xor(a[j], 32, 64);
        }
        if (lane < 16) {
            float inv = (c > 0) ? 1.f / (float)c : 0.f;
            uint4 w;
            w.x = pk2(a[0] * inv, a[1] * inv);
            w.y = pk2(a[2] * inv, a[3] * inv);
            w.z = pk2(a[4] * inv, a[5] * inv);
            w.w = pk2(a[6] * inv, a[7] * inv);
            *reinterpret_cast<uint4*>(CS + obase + r * HID + colb) = w;
        }
    }
}

// MFMA GEMM: out[M pad][128] = CS[M][640] @ W[640][128] via Wt[128][640].
// Block: 64 rows x 128 cols, 4 waves; wave w covers rows x cols [32w,32w+32).
template <int MODE>
__launch_bounds__(256)
__global__ void k_gemm(const short* __restrict__ A, const short* __restrict__ Wt,
                       const float* __restrict__ bias, short* __restrict__ outb) {
    const int wave = threadIdx.x >> 6, lane = threadIdx.x & 63;
    const int m0 = blockIdx.x * 64;
    const int col0 = wave * 32;
    const int q = lane & 15;
    const int kq = (lane >> 4) * 8;
    const short* ap = A + (size_t)(m0 + q) * KCAT + kq;
    const short* bp = Wt + (size_t)(col0 + q) * KCAT + kq;
    f32x4 acc[4][2];
#pragma unroll
    for (int i = 0; i < 4; i++)
#pragma unroll
        for (int j = 0; j < 2; j++) acc[i][j] = (f32x4){0.f, 0.f, 0.f, 0.f};
    for (int kk = 0; kk < KCAT / 32; ++kk) {
        const int ko = kk * 32;
        bf16x8 b0 = *reinterpret_cast<const bf16x8*>(bp + ko);
        bf16x8 b1 = *reinterpret_cast<const bf16x8*>(bp + (size_t)16 * KCAT + ko);
#pragma unroll
        for (int rf = 0; rf < 4; ++rf) {
            bf16x8 a = *reinterpret_cast<const bf16x8*>(ap + (size_t)rf * 16 * KCAT + ko);
            acc[rf][0] = __builtin_amdgcn_mfma_f32_16x16x32_bf16(a, b0, acc[rf][0], 0, 0, 0);
            acc[rf][1] = __builtin_amdgcn_mfma_f32_16x16x32_bf16(a, b1, acc[rf][1], 0, 0, 0);
        }
    }
    const int rq = (lane >> 4) * 4;
#pragma unroll
    for (int rf = 0; rf < 4; ++rf) {
#pragma unroll
        for (int cf = 0; cf < 2; ++cf) {
            const int col = col0 + cf * 16 + q;
#pragma unroll
            for (int r = 0; r < 4; ++r) {
                const int row = m0 + rf * 16 + rq + r;
                if (row < N_NODES) {
                    float v = acc[rf][cf][r];
                    if (MODE == 1) {
                        v = fmaxf(v + bias[col], 0.f);
                        outb[(size_t)row * KCAT + 512 + col] = (short)f2bf(v);
                    } else {
                        outb[(size_t)row * HID + col] = (short)f2bf(v);
                    }
                }
            }
        }
    }
}

// segmented pool over sorted batch; 4 blocks/graph; bias2 folded (x node count)
__global__ void k_pool(const short* __restrict__ h2b, const float* __restrict__ bias2,
                       const int* __restrict__ batch, float* __restrict__ g) {
    __shared__ int s_lo, s_hi;
    int gi = blockIdx.x, qb = blockIdx.y, t = threadIdx.x;
    if (t == 0) {
        int lo = 0, hi = N_NODES;
        while (lo < hi) { int m = (lo + hi) >> 1; if (batch[m] < gi) lo = m + 1; else hi = m; }
        s_lo = lo;
        int lo2 = lo, hi2 = N_NODES;
        while (lo2 < hi2) { int m = (lo2 + hi2) >> 1; if (batch[m] < gi + 1) lo2 = m + 1; else hi2 = m; }
        s_hi = lo2;
    }
    __syncthreads();
    int lo = s_lo, hi = s_hi;
    float acc = 0.f;
    for (int n = lo + qb; n < hi; n += 4)
        acc += bf2f((unsigned short)h2b[(size_t)n * HID + t]);
    if (qb == 0) acc += (float)(hi - lo) * bias2[t];
    atomicAdd(&g[gi * HID + t], acc);
}

// per-graph: relu(g @ fc_w + fc_b) -> log_softmax
__global__ void k_fc(const float* __restrict__ g, const float* __restrict__ fcw,
                     const float* __restrict__ fcb, float* __restrict__ out) {
    __shared__ float vals[N_CLS];
    __shared__ float s_lse;
    int gi = blockIdx.x, t = threadIdx.x;
    if (t < N_CLS) {
        float acc = fcb[t];
        const float* gr = g + (size_t)gi * HID;
        for (int k = 0; k < HID; k++) acc = fmaf(gr[k], fcw[k * N_CLS + t], acc);
        vals[t] = fmaxf(acc, 0.f);
    }
    __syncthreads();
    if (t == 0) {
        float m = vals[0];
        for (int c = 1; c < N_CLS; c++) m = fmaxf(m, vals[c]);
        float ssum = 0.f;
        for (int c = 0; c < N_CLS; c++) ssum += expf(vals[c] - m);
        s_lse = m + logf(ssum);
    }
    __syncthreads();
    if (t < N_CLS) out[gi * N_CLS + t] = vals[t] - s_lse;
}

extern "C" void kernel_launch(void* const* d_in, const int* in_sizes, int n_in,
                              void* d_out, int out_size, void* d_ws, size_t ws_size,
                              hipStream_t stream) {
    const float* x      = (const float*)d_in[0];
    const int*   ei     = (const int*)d_in[1];
    const int*   src    = ei;
    const int*   dst    = ei + N_EDGES;
    const int*   et     = (const int*)d_in[2];
    const int*   batch  = (const int*)d_in[3];
    const float* basis1 = (const float*)d_in[4];
    const float* comp1  = (const float*)d_in[5];
    const float* root1  = (const float*)d_in[6];
    const float* bias1  = (const float*)d_in[7];
    const float* basis2 = (const float*)d_in[8];
    const float* comp2  = (const float*)d_in[9];
    const float* root2  = (const float*)d_in[10];
    const float* bias2  = (const float*)d_in[11];
    const float* fcw    = (const float*)d_in[12];
    const float* fcb    = (const float*)d_in[13];
    float* out = (float*)d_out;

    // workspace layout (~164 MB)
    short* CS   = (short*)d_ws;                        // [100032][640] bf16
    short* h2b  = CS + (size_t)N_ROWS * KCAT;          // [100000][128] bf16
    int*   rank = (int*)h2b;                           // [E] — aliases h2b (disjoint lifetime)
    short* Wt1  = h2b + (size_t)N_NODES * HID;         // [128][640] bf16
    short* Wt2  = Wt1 + HID * KCAT;                    // [128][640] bf16
    float* g    = (float*)(Wt2 + HID * KCAT);          // [512][128] f32
    int*   cnt  = (int*)(g + N_GRAPH * HID);           // SEG
    int*   off  = cnt + SEG;
    int*   bsum = off + SEG;                           // 512
    int*   ssrc = bsum + 512;                          // E

    hipMemsetAsync(cnt, 0, SEG * sizeof(int), stream);
    hipMemsetAsync(g, 0, (size_t)N_GRAPH * HID * sizeof(float), stream);

    k_wt<FIN><<<(KCAT * HID + 255) / 256, 256, 0, stream>>>(basis1, comp1, root1, Wt1);
    k_wt<HID><<<(KCAT * HID + 255) / 256, 256, 0, stream>>>(basis2, comp2, root2, Wt2);
    k_xcvt<<<(N_NODES * HID + 255) / 256, 256, 0, stream>>>(x, CS);

    // CSR build by (relation, dst): count(+rank) -> scan -> scatter
    k_count<<<(N_EDGES + 255) / 256, 256, 0, stream>>>(et, dst, cnt, rank);
    k_bsum<<<NB_SCAN, 256, 0, stream>>>(cnt, bsum);
    k_bpref<<<1, 64, 0, stream>>>(bsum, NB_SCAN);
    k_offsets<<<NB_SCAN, 256, 0, stream>>>(cnt, bsum, off);
    k_scatter<<<(N_EDGES + 255) / 256, 256, 0, stream>>>(et, src, dst, off, rank, ssrc);

    const int AGG_GRID  = N_NODES / 4;     // 1 wave/node, 4 waves/block
    const int GEMM_GRID = N_ROWS / 64;     // 1563

    // layer 1
    k_agg2<<<AGG_GRID, 256, 0, stream>>>(off, cnt, ssrc, CS);
    k_gemm<1><<<GEMM_GRID, 256, 0, stream>>>(CS, Wt1, bias1, CS);

    // layer 2 (bias2 folded into pool)
    k_agg2<<<AGG_GRID, 256, 0, stream>>>(off, cnt, ssrc, CS);
    k_gemm<2><<<GEMM_GRID, 256, 0, stream>>>(CS, Wt2, nullptr, h2b);

    // pool + fc + log_softmax
    k_pool<<<dim3(N_GRAPH, 4), HID, 0, stream>>>(h2b, bias2, batch, g);
    k_fc<<<N_GRAPH, 64, 0, stream>>>(g, fcw, fcb, out);
}

// Round 5
// 541.196 us; speedup vs baseline: 5.6292x; 1.1473x over previous
//
#include <hip/hip_runtime.h>
#include <hip/hip_bf16.h>
#include <cstddef>
#include <cstdint>

#define N_NODES 100000
#define N_ROWS  100032            // padded to 64-row blocks
#define DUMMY   100000            // zeroed pad row inside CS (feature block kept 0)
#define N_EDGES 1600000
#define N_REL   4
#define N_BASES 30
#define FIN     86
#define HID     128
#define N_CLS   18
#define N_GRAPH 512
#define KCAT    640               // 4 relation blocks + root block, 128 each

#define SEG (N_REL * N_NODES)                         // 400000 segments
#define SSRC_MAX (N_EDGES + 3 * SEG)                  // padded CSR worst case = 2.8M
#define SCAN_CHUNK 1024
#define NB_SCAN ((SEG + SCAN_CHUNK - 1) / SCAN_CHUNK) // 391

typedef __attribute__((ext_vector_type(8))) short bf16x8;
typedef __attribute__((ext_vector_type(4))) float f32x4;

__device__ inline float blo(unsigned int u) {
    union { unsigned int i; float f; } c; c.i = u << 16; return c.f;
}
__device__ inline float bhi(unsigned int u) {
    union { unsigned int i; float f; } c; c.i = u & 0xffff0000u; return c.f;
}
__device__ inline unsigned short f2bf(float f) {
    __hip_bfloat16 h = __float2bfloat16(f);
    return *reinterpret_cast<unsigned short*>(&h);
}
__device__ inline unsigned int pk2(float lo, float hi) {
    return (unsigned int)f2bf(lo) | ((unsigned int)f2bf(hi) << 16);
}
__device__ inline int pad4i(int x) { return (x + 3) & ~3; }

// Stacked transposed weights: Wt[n][s], s = r*128+k (r<4: sum_b comp*basis) or 512+k (root).
template <int KV>
__global__ void k_wt(const float* __restrict__ basis, const float* __restrict__ comp,
                     const float* __restrict__ root, short* __restrict__ Wt) {
    int id = blockIdx.x * 256 + threadIdx.x;
    if (id >= KCAT * HID) return;
    int n = id & 127, s = id >> 7;
    int k = s & 127, blk = s >> 7;
    float v = 0.f;
    if (k < KV) {
        if (blk < N_REL) {
#pragma unroll
            for (int b = 0; b < N_BASES; ++b)
                v += comp[blk * N_BASES + b] * basis[((size_t)b * KV + k) * HID + n];
        } else {
            v = root[k * HID + n];
        }
    }
    Wt[(size_t)n * KCAT + s] = (short)f2bf(v);
}

// x[N,86] f32 -> CS[:, 512..639] bf16 (zero pad k>=86); also zeroes DUMMY row's block
__global__ void k_xcvt(const float* __restrict__ x, short* __restrict__ CS) {
    int id = blockIdx.x * 256 + threadIdx.x;
    if (id >= (N_NODES + 1) * HID) return;
    int n = id >> 7, k = id & 127;
    float v = (n < N_NODES && k < FIN) ? x[n * FIN + k] : 0.f;
    CS[(size_t)n * KCAT + 512 + k] = (short)f2bf(v);
}

// prefill padded CSR with DUMMY
__global__ void k_fill(int* __restrict__ p) {
    int i = blockIdx.x * 256 + threadIdx.x;
    if (i < SSRC_MAX) p[i] = DUMMY;
}

// histogram + per-edge rank in one atomic pass
__global__ void k_count(const int* __restrict__ et, const int* __restrict__ dst,
                        int* __restrict__ cnt, int* __restrict__ rank) {
    int e = blockIdx.x * 256 + threadIdx.x;
    if (e >= N_EDGES) return;
    rank[e] = atomicAdd(cnt + et[e] * N_NODES + dst[e], 1);
}

// ---- 3-kernel exclusive scan of pad4(cnt[SEG]) -> off[SEG] (padded offsets) ----
__global__ void k_bsum(const int* __restrict__ cnt, int* __restrict__ bsum) {
    __shared__ int red[256];
    int base = blockIdx.x * SCAN_CHUNK + threadIdx.x * 4;
    int s = 0;
#pragma unroll
    for (int j = 0; j < 4; j++) { int idx = base + j; if (idx < SEG) s += pad4i(cnt[idx]); }
    red[threadIdx.x] = s;
    __syncthreads();
    for (int w = 128; w > 0; w >>= 1) {
        if (threadIdx.x < w) red[threadIdx.x] += red[threadIdx.x + w];
        __syncthreads();
    }
    if (threadIdx.x == 0) bsum[blockIdx.x] = red[0];
}

__global__ void k_bpref(int* bsum, int nb) {
    if (threadIdx.x == 0 && blockIdx.x == 0) {
        int run = 0;
        for (int i = 0; i < nb; i++) { int t = bsum[i]; bsum[i] = run; run += t; }
    }
}

__global__ void k_offsets(const int* __restrict__ cnt, const int* __restrict__ bpref,
                          int* __restrict__ off) {
    __shared__ int tp[256];
    int t = threadIdx.x;
    int base = blockIdx.x * SCAN_CHUNK + t * 4;
    int v[4], s = 0;
#pragma unroll
    for (int j = 0; j < 4; j++) { int idx = base + j; v[j] = (idx < SEG) ? pad4i(cnt[idx]) : 0; s += v[j]; }
    tp[t] = s;
    __syncthreads();
    if (t == 0) { int run = 0; for (int i = 0; i < 256; i++) { int x = tp[i]; tp[i] = run; run += x; } }
    __syncthreads();
    int p = bpref[blockIdx.x] + tp[t];
#pragma unroll
    for (int j = 0; j < 4; j++) { int idx = base + j; if (idx < SEG) off[idx] = p; p += v[j]; }
}

// atomic-free scatter using precomputed rank (pad slots keep DUMMY)
__global__ void k_scatter(const int* __restrict__ et, const int* __restrict__ srcI,
                          const int* __restrict__ dstI, const int* __restrict__ off,
                          const int* __restrict__ rank, int* __restrict__ ssrc) {
    int e = blockIdx.x * 256 + threadIdx.x;
    if (e >= N_EDGES) return;
    int seg = et[e] * N_NODES + dstI[e];
    ssrc[off[seg] + rank[e]] = srcI[e];
}

// one wave per node; 4 groups x 16 lanes = 4 RELATIONS in parallel (no shuffles).
// Each group walks its padded segment in 4-edge chunks: 1 int4 ssrc load +
// 4 independent uint4 gathers in flight. Dummy rows contribute 0.
__global__ void k_agg2(const int* __restrict__ off, const int* __restrict__ cnt,
                       const int* __restrict__ ssrc, short* __restrict__ CS) {
    int node = (blockIdx.x * 256 + threadIdx.x) >> 6;
    int lane = threadIdx.x & 63;
    if (node >= N_NODES) return;
    const int r = lane >> 4, q = lane & 15;
    const int colb = q * 8;
    int seg = r * N_NODES + node;
    int o0 = off[seg], c = cnt[seg];
    int nch = (c + 3) >> 2;
    float a[8];
#pragma unroll
    for (int j = 0; j < 8; j++) a[j] = 0.f;
    const int4* sp = reinterpret_cast<const int4*>(ssrc + o0);
    for (int ch = 0; ch < nch; ++ch) {
        int4 e4 = sp[ch];
        uint4 v0 = *reinterpret_cast<const uint4*>(CS + (size_t)e4.x * KCAT + 512 + colb);
        uint4 v1 = *reinterpret_cast<const uint4*>(CS + (size_t)e4.y * KCAT + 512 + colb);
        uint4 v2 = *reinterpret_cast<const uint4*>(CS + (size_t)e4.z * KCAT + 512 + colb);
        uint4 v3 = *reinterpret_cast<const uint4*>(CS + (size_t)e4.w * KCAT + 512 + colb);
        a[0] += blo(v0.x); a[1] += bhi(v0.x); a[2] += blo(v0.y); a[3] += bhi(v0.y);
        a[4] += blo(v0.z); a[5] += bhi(v0.z); a[6] += blo(v0.w); a[7] += bhi(v0.w);
        a[0] += blo(v1.x); a[1] += bhi(v1.x); a[2] += blo(v1.y); a[3] += bhi(v1.y);
        a[4] += blo(v1.z); a[5] += bhi(v1.z); a[6] += blo(v1.w); a[7] += bhi(v1.w);
        a[0] += blo(v2.x); a[1] += bhi(v2.x); a[2] += blo(v2.y); a[3] += bhi(v2.y);
        a[4] += blo(v2.z); a[5] += bhi(v2.z); a[6] += blo(v2.w); a[7] += bhi(v2.w);
        a[0] += blo(v3.x); a[1] += bhi(v3.x); a[2] += blo(v3.y); a[3] += bhi(v3.y);
        a[4] += blo(v3.z); a[5] += bhi(v3.z); a[6] += blo(v3.w); a[7] += bhi(v3.w);
    }
    float inv = (c > 0) ? 1.f / (float)c : 0.f;
    uint4 w;
    w.x = pk2(a[0] * inv, a[1] * inv);
    w.y = pk2(a[2] * inv, a[3] * inv);
    w.z = pk2(a[4] * inv, a[5] * inv);
    w.w = pk2(a[6] * inv, a[7] * inv);
    *reinterpret_cast<uint4*>(CS + (size_t)node * KCAT + r * HID + colb) = w;
}

// MFMA GEMM: out[M pad][128] = CS[M][640] @ W[640][128] via Wt[128][640].
// Block: 64 rows x 128 cols, 4 waves; wave w covers rows x cols [32w,32w+32).
// MODE 1: relu(.+bias) -> bf16 h1 into CS[:,512..]. MODE 2: fused pool — per-lane
// run-compress rows by sorted batch[], ~2 atomicAdds/col into g (bias2 folded in fc).
template <int MODE>
__launch_bounds__(256)
__global__ void k_gemm(const short* __restrict__ A, const short* __restrict__ Wt,
                       const float* __restrict__ bias, short* __restrict__ outb,
                       const int* __restrict__ batch, float* __restrict__ g) {
    const int wave = threadIdx.x >> 6, lane = threadIdx.x & 63;
    const int m0 = blockIdx.x * 64;
    const int col0 = wave * 32;
    const int q = lane & 15;
    const int kq = (lane >> 4) * 8;
    const short* ap = A + (size_t)(m0 + q) * KCAT + kq;
    const short* bp = Wt + (size_t)(col0 + q) * KCAT + kq;
    f32x4 acc[4][2];
#pragma unroll
    for (int i = 0; i < 4; i++)
#pragma unroll
        for (int j = 0; j < 2; j++) acc[i][j] = (f32x4){0.f, 0.f, 0.f, 0.f};
    for (int kk = 0; kk < KCAT / 32; ++kk) {
        const int ko = kk * 32;
        bf16x8 b0 = *reinterpret_cast<const bf16x8*>(bp + ko);
        bf16x8 b1 = *reinterpret_cast<const bf16x8*>(bp + (size_t)16 * KCAT + ko);
#pragma unroll
        for (int rf = 0; rf < 4; ++rf) {
            bf16x8 a = *reinterpret_cast<const bf16x8*>(ap + (size_t)rf * 16 * KCAT + ko);
            acc[rf][0] = __builtin_amdgcn_mfma_f32_16x16x32_bf16(a, b0, acc[rf][0], 0, 0, 0);
            acc[rf][1] = __builtin_amdgcn_mfma_f32_16x16x32_bf16(a, b1, acc[rf][1], 0, 0, 0);
        }
    }
    const int rq = (lane >> 4) * 4;
    if (MODE == 1) {
#pragma unroll
        for (int rf = 0; rf < 4; ++rf) {
#pragma unroll
            for (int cf = 0; cf < 2; ++cf) {
                const int col = col0 + cf * 16 + q;
#pragma unroll
                for (int r = 0; r < 4; ++r) {
                    const int row = m0 + rf * 16 + rq + r;
                    if (row < N_NODES) {
                        float v = fmaxf(acc[rf][cf][r] + bias[col], 0.f);
                        outb[(size_t)row * KCAT + 512 + col] = (short)f2bf(v);
                    }
                }
            }
        }
    } else {
        // fused global_add_pool: rows ascending per lane, batch sorted -> short runs
        const int colA = col0 + q, colB = col0 + 16 + q;
        int curb = -1;
        float run0 = 0.f, run1 = 0.f;
#pragma unroll
        for (int rf = 0; rf < 4; ++rf) {
#pragma unroll
            for (int r = 0; r < 4; ++r) {
                const int row = m0 + rf * 16 + rq + r;
                if (row < N_NODES) {
                    int b = batch[row];
                    if (b != curb) {
                        if (curb >= 0) {
                            atomicAdd(&g[curb * HID + colA], run0);
                            atomicAdd(&g[curb * HID + colB], run1);
                        }
                        curb = b; run0 = 0.f; run1 = 0.f;
                    }
                    run0 += acc[rf][0][r];
                    run1 += acc[rf][1][r];
                }
            }
        }
        if (curb >= 0) {
            atomicAdd(&g[curb * HID + colA], run0);
            atomicAdd(&g[curb * HID + colB], run1);
        }
    }
}

// per-graph: pooled = g + cnt*bias2; relu(pooled @ fc_w + fc_b) -> log_softmax
__global__ void k_fc(const float* __restrict__ g, const float* __restrict__ bias2,
                     const int* __restrict__ batch, const float* __restrict__ fcw,
                     const float* __restrict__ fcb, float* __restrict__ out) {
    __shared__ float pooled[HID];
    __shared__ float vals[N_CLS];
    __shared__ float s_lse;
    __shared__ int s_cnt;
    int gi = blockIdx.x, t = threadIdx.x;
    if (t == 0) {
        int lo = 0, hi = N_NODES;
        while (lo < hi) { int m = (lo + hi) >> 1; if (batch[m] < gi) lo = m + 1; else hi = m; }
        int lo2 = lo, hi2 = N_NODES;
        while (lo2 < hi2) { int m = (lo2 + hi2) >> 1; if (batch[m] < gi + 1) lo2 = m + 1; else hi2 = m; }
        s_cnt = lo2 - lo;
    }
    __syncthreads();
    pooled[t] = g[gi * HID + t] + (float)s_cnt * bias2[t];
    __syncthreads();
    if (t < N_CLS) {
        float acc = fcb[t];
        for (int k = 0; k < HID; k++) acc = fmaf(pooled[k], fcw[k * N_CLS + t], acc);
        vals[t] = fmaxf(acc, 0.f);
    }
    __syncthreads();
    if (t == 0) {
        float m = vals[0];
        for (int c = 1; c < N_CLS; c++) m = fmaxf(m, vals[c]);
        float ssum = 0.f;
        for (int c = 0; c < N_CLS; c++) ssum += expf(vals[c] - m);
        s_lse = m + logf(ssum);
    }
    __syncthreads();
    if (t < N_CLS) out[gi * N_CLS + t] = vals[t] - s_lse;
}

extern "C" void kernel_launch(void* const* d_in, const int* in_sizes, int n_in,
                              void* d_out, int out_size, void* d_ws, size_t ws_size,
                              hipStream_t stream) {
    const float* x      = (const float*)d_in[0];
    const int*   ei     = (const int*)d_in[1];
    const int*   src    = ei;
    const int*   dst    = ei + N_EDGES;
    const int*   et     = (const int*)d_in[2];
    const int*   batch  = (const int*)d_in[3];
    const float* basis1 = (const float*)d_in[4];
    const float* comp1  = (const float*)d_in[5];
    const float* root1  = (const float*)d_in[6];
    const float* bias1  = (const float*)d_in[7];
    const float* basis2 = (const float*)d_in[8];
    const float* comp2  = (const float*)d_in[9];
    const float* root2  = (const float*)d_in[10];
    const float* bias2  = (const float*)d_in[11];
    const float* fcw    = (const float*)d_in[12];
    const float* fcb    = (const float*)d_in[13];
    float* out = (float*)d_out;

    // workspace layout (~150 MB)
    short* CS   = (short*)d_ws;                        // [100032][640] bf16 = 128.04 MB
    short* Wt1  = CS + (size_t)N_ROWS * KCAT;          // [128][640] bf16
    short* Wt2  = Wt1 + HID * KCAT;                    // [128][640] bf16
    float* g    = (float*)(Wt2 + HID * KCAT);          // [512][128] f32
    int*   cnt  = (int*)(g + N_GRAPH * HID);           // SEG
    int*   off  = cnt + SEG;                           // SEG (padded offsets)
    int*   bsum = off + SEG;                           // 512
    int*   rank = bsum + 512;                          // E
    int*   ssrc = rank + N_EDGES;                      // SSRC_MAX (padded CSR)

    hipMemsetAsync(cnt, 0, SEG * sizeof(int), stream);
    hipMemsetAsync(g, 0, (size_t)N_GRAPH * HID * sizeof(float), stream);

    k_wt<FIN><<<(KCAT * HID + 255) / 256, 256, 0, stream>>>(basis1, comp1, root1, Wt1);
    k_wt<HID><<<(KCAT * HID + 255) / 256, 256, 0, stream>>>(basis2, comp2, root2, Wt2);
    k_xcvt<<<((N_NODES + 1) * HID + 255) / 256, 256, 0, stream>>>(x, CS);
    k_fill<<<(SSRC_MAX + 255) / 256, 256, 0, stream>>>(ssrc);

    // CSR build by (relation, dst): count(+rank) -> padded scan -> scatter
    k_count<<<(N_EDGES + 255) / 256, 256, 0, stream>>>(et, dst, cnt, rank);
    k_bsum<<<NB_SCAN, 256, 0, stream>>>(cnt, bsum);
    k_bpref<<<1, 64, 0, stream>>>(bsum, NB_SCAN);
    k_offsets<<<NB_SCAN, 256, 0, stream>>>(cnt, bsum, off);
    k_scatter<<<(N_EDGES + 255) / 256, 256, 0, stream>>>(et, src, dst, off, rank, ssrc);

    const int AGG_GRID  = N_NODES / 4;     // 1 wave/node, 4 waves/block
    const int GEMM_GRID = N_ROWS / 64;     // 1563

    // layer 1
    k_agg2<<<AGG_GRID, 256, 0, stream>>>(off, cnt, ssrc, CS);
    k_gemm<1><<<GEMM_GRID, 256, 0, stream>>>(CS, Wt1, bias1, CS, nullptr, nullptr);

    // layer 2 (pool fused into epilogue; bias2 folded into fc)
    k_agg2<<<AGG_GRID, 256, 0, stream>>>(off, cnt, ssrc, CS);
    k_gemm<2><<<GEMM_GRID, 256, 0, stream>>>(CS, Wt2, nullptr, nullptr, batch, g);

    // fc + log_softmax (with bias2 * node-count fold)
    k_fc<<<N_GRAPH, HID, 0, stream>>>(g, bias2, batch, fcw, fcb, out);
}

// Round 6
// 497.506 us; speedup vs baseline: 6.1235x; 1.0878x over previous
//
#include <hip/hip_runtime.h>
#include <hip/hip_bf16.h>
#include <cstddef>
#include <cstdint>

#define N_NODES 100000
#define N_ROWS  100032            // padded to 32-row blocks
#define DUMMY   100000            // zeroed pad row inside CS (feature block kept 0)
#define N_EDGES 1600000
#define N_REL   4
#define N_BASES 30
#define FIN     86
#define HID     128
#define N_CLS   18
#define N_GRAPH 512
#define KCAT    640               // 4 relation blocks + root block, 128 each
#define BM      32                // gemm rows per block

#define SEG (N_REL * N_NODES)                         // 400000 segments
#define SSRC_MAX (N_EDGES + 3 * SEG)                  // padded CSR worst case = 2.8M
#define SCAN_CHUNK 1024
#define NB_SCAN ((SEG + SCAN_CHUNK - 1) / SCAN_CHUNK) // 391

typedef __attribute__((ext_vector_type(8))) short bf16x8;
typedef __attribute__((ext_vector_type(4))) float f32x4;

__device__ inline float blo(unsigned int u) {
    union { unsigned int i; float f; } c; c.i = u << 16; return c.f;
}
__device__ inline float bhi(unsigned int u) {
    union { unsigned int i; float f; } c; c.i = u & 0xffff0000u; return c.f;
}
__device__ inline unsigned short f2bf(float f) {
    __hip_bfloat16 h = __float2bfloat16(f);
    return *reinterpret_cast<unsigned short*>(&h);
}
__device__ inline unsigned int pk2(float lo, float hi) {
    return (unsigned int)f2bf(lo) | ((unsigned int)f2bf(hi) << 16);
}
__device__ inline int pad4i(int x) { return (x + 3) & ~3; }

// Stacked transposed weights: Wt[n][s], s = r*128+k (r<4: sum_b comp*basis) or 512+k (root).
template <int KV>
__global__ void k_wt(const float* __restrict__ basis, const float* __restrict__ comp,
                     const float* __restrict__ root, short* __restrict__ Wt) {
    int id = blockIdx.x * 256 + threadIdx.x;
    if (id >= KCAT * HID) return;
    int n = id & 127, s = id >> 7;
    int k = s & 127, blk = s >> 7;
    float v = 0.f;
    if (k < KV) {
        if (blk < N_REL) {
#pragma unroll
            for (int b = 0; b < N_BASES; ++b)
                v += comp[blk * N_BASES + b] * basis[((size_t)b * KV + k) * HID + n];
        } else {
            v = root[k * HID + n];
        }
    }
    Wt[(size_t)n * KCAT + s] = (short)f2bf(v);
}

// x[N,86] f32 -> CS[:, 512..639] bf16 (zero pad k>=86); also zeroes DUMMY row's block
__global__ void k_xcvt(const float* __restrict__ x, short* __restrict__ CS) {
    int id = blockIdx.x * 256 + threadIdx.x;
    if (id >= (N_NODES + 1) * HID) return;
    int n = id >> 7, k = id & 127;
    float v = (n < N_NODES && k < FIN) ? x[n * FIN + k] : 0.f;
    CS[(size_t)n * KCAT + 512 + k] = (short)f2bf(v);
}

// prefill padded CSR with DUMMY
__global__ void k_fill(int* __restrict__ p) {
    int i = blockIdx.x * 256 + threadIdx.x;
    if (i < SSRC_MAX) p[i] = DUMMY;
}

// histogram + per-edge rank in one atomic pass
__global__ void k_count(const int* __restrict__ et, const int* __restrict__ dst,
                        int* __restrict__ cnt, int* __restrict__ rank) {
    int e = blockIdx.x * 256 + threadIdx.x;
    if (e >= N_EDGES) return;
    rank[e] = atomicAdd(cnt + et[e] * N_NODES + dst[e], 1);
}

// ---- 3-kernel exclusive scan of pad4(cnt[SEG]) -> off[SEG] (padded offsets) ----
__global__ void k_bsum(const int* __restrict__ cnt, int* __restrict__ bsum) {
    __shared__ int red[256];
    int base = blockIdx.x * SCAN_CHUNK + threadIdx.x * 4;
    int s = 0;
#pragma unroll
    for (int j = 0; j < 4; j++) { int idx = base + j; if (idx < SEG) s += pad4i(cnt[idx]); }
    red[threadIdx.x] = s;
    __syncthreads();
    for (int w = 128; w > 0; w >>= 1) {
        if (threadIdx.x < w) red[threadIdx.x] += red[threadIdx.x + w];
        __syncthreads();
    }
    if (threadIdx.x == 0) bsum[blockIdx.x] = red[0];
}

__global__ void k_bpref(int* bsum, int nb) {
    if (threadIdx.x == 0 && blockIdx.x == 0) {
        int run = 0;
        for (int i = 0; i < nb; i++) { int t = bsum[i]; bsum[i] = run; run += t; }
    }
}

__global__ void k_offsets(const int* __restrict__ cnt, const int* __restrict__ bpref,
                          int* __restrict__ off) {
    __shared__ int tp[256];
    int t = threadIdx.x;
    int base = blockIdx.x * SCAN_CHUNK + t * 4;
    int v[4], s = 0;
#pragma unroll
    for (int j = 0; j < 4; j++) { int idx = base + j; v[j] = (idx < SEG) ? pad4i(cnt[idx]) : 0; s += v[j]; }
    tp[t] = s;
    __syncthreads();
    if (t == 0) { int run = 0; for (int i = 0; i < 256; i++) { int x = tp[i]; tp[i] = run; run += x; } }
    __syncthreads();
    int p = bpref[blockIdx.x] + tp[t];
#pragma unroll
    for (int j = 0; j < 4; j++) { int idx = base + j; if (idx < SEG) off[idx] = p; p += v[j]; }
}

// atomic-free scatter using precomputed rank (pad slots keep DUMMY)
__global__ void k_scatter(const int* __restrict__ et, const int* __restrict__ srcI,
                          const int* __restrict__ dstI, const int* __restrict__ off,
                          const int* __restrict__ rank, int* __restrict__ ssrc) {
    int e = blockIdx.x * 256 + threadIdx.x;
    if (e >= N_EDGES) return;
    int seg = et[e] * N_NODES + dstI[e];
    ssrc[off[seg] + rank[e]] = srcI[e];
}

// one wave per node; 4 groups x 16 lanes = 4 RELATIONS in parallel (no shuffles).
// Each group walks its padded segment in 4-edge chunks: 1 int4 ssrc load +
// 4 independent uint4 gathers in flight. Dummy rows contribute 0.
__global__ void k_agg2(const int* __restrict__ off, const int* __restrict__ cnt,
                       const int* __restrict__ ssrc, short* __restrict__ CS) {
    int node = (blockIdx.x * 256 + threadIdx.x) >> 6;
    int lane = threadIdx.x & 63;
    if (node >= N_NODES) return;
    const int r = lane >> 4, q = lane & 15;
    const int colb = q * 8;
    int seg = r * N_NODES + node;
    int o0 = off[seg], c = cnt[seg];
    int nch = (c + 3) >> 2;
    float a[8];
#pragma unroll
    for (int j = 0; j < 8; j++) a[j] = 0.f;
    const int4* sp = reinterpret_cast<const int4*>(ssrc + o0);
    for (int ch = 0; ch < nch; ++ch) {
        int4 e4 = sp[ch];
        uint4 v0 = *reinterpret_cast<const uint4*>(CS + (size_t)e4.x * KCAT + 512 + colb);
        uint4 v1 = *reinterpret_cast<const uint4*>(CS + (size_t)e4.y * KCAT + 512 + colb);
        uint4 v2 = *reinterpret_cast<const uint4*>(CS + (size_t)e4.z * KCAT + 512 + colb);
        uint4 v3 = *reinterpret_cast<const uint4*>(CS + (size_t)e4.w * KCAT + 512 + colb);
        a[0] += blo(v0.x); a[1] += bhi(v0.x); a[2] += blo(v0.y); a[3] += bhi(v0.y);
        a[4] += blo(v0.z); a[5] += bhi(v0.z); a[6] += blo(v0.w); a[7] += bhi(v0.w);
        a[0] += blo(v1.x); a[1] += bhi(v1.x); a[2] += blo(v1.y); a[3] += bhi(v1.y);
        a[4] += blo(v1.z); a[5] += bhi(v1.z); a[6] += blo(v1.w); a[7] += bhi(v1.w);
        a[0] += blo(v2.x); a[1] += bhi(v2.x); a[2] += blo(v2.y); a[3] += bhi(v2.y);
        a[4] += blo(v2.z); a[5] += bhi(v2.z); a[6] += blo(v2.w); a[7] += bhi(v2.w);
        a[0] += blo(v3.x); a[1] += bhi(v3.x); a[2] += blo(v3.y); a[3] += bhi(v3.y);
        a[4] += blo(v3.z); a[5] += bhi(v3.z); a[6] += blo(v3.w); a[7] += bhi(v3.w);
    }
    float inv = (c > 0) ? 1.f / (float)c : 0.f;
    uint4 w;
    w.x = pk2(a[0] * inv, a[1] * inv);
    w.y = pk2(a[2] * inv, a[3] * inv);
    w.z = pk2(a[4] * inv, a[5] * inv);
    w.w = pk2(a[6] * inv, a[7] * inv);
    *reinterpret_cast<uint4*>(CS + (size_t)node * KCAT + r * HID + colb) = w;
}

// MFMA GEMM: out[M pad][128] = CS[M][640] @ W[640][128] via Wt[128][640].
// Block: BM=32 rows x 128 cols, 4 waves; wave w covers cols [32w,32w+32).
// A-tile (contiguous 40 KB) reg-staged into LDS with XOR swizzle
// (byte ^ ((row&7)<<4)) -> conflict-free ds_read_b128 fragments.
// MODE 1: relu(.+bias) -> bf16 h1 into CS[:,512..]. MODE 2: fused pool — per-lane
// run-compress rows by sorted batch[], ~2 atomicAdds/col into g (bias2 folded in fc).
template <int MODE>
__launch_bounds__(256)
__global__ void k_gemm(const short* __restrict__ A, const short* __restrict__ Wt,
                       const float* __restrict__ bias, short* __restrict__ outb,
                       const int* __restrict__ batch, float* __restrict__ g) {
    __shared__ short As[BM * KCAT];                 // 40960 B
    const int tid = threadIdx.x;
    const int wave = tid >> 6, lane = tid & 63;
    const int m0 = blockIdx.x * BM;

    // ---- stage A tile (one contiguous 40 KB span) into LDS, swizzled ----
    {
        const uint4* gsrc = reinterpret_cast<const uint4*>(A + (size_t)m0 * KCAT);
        uint4 tmp[10];
#pragma unroll
        for (int i = 0; i < 10; ++i) tmp[i] = gsrc[i * 256 + tid];
#pragma unroll
        for (int i = 0; i < 10; ++i) {
            int u = i * 256 + tid;                  // 16B unit index
            int row = u / 80;                       // 80 units per 1280 B row
            int p = (u * 16) ^ ((row & 7) << 4);
            *reinterpret_cast<uint4*>(reinterpret_cast<char*>(As) + p) = tmp[i];
        }
    }
    __syncthreads();

    const int col0 = wave * 32;
    const int q = lane & 15, hi = lane >> 4;
    const int kq = hi * 8;
    const short* bp = Wt + (size_t)(col0 + q) * KCAT + kq;
    const char* Ab = reinterpret_cast<const char*>(As);
    const int bx = (hi << 4) ^ ((q & 7) << 4);      // lane's swizzled k-slot bits
    const int arow = q * (KCAT * 2);                // row q byte base (rf adds 16 rows)

    f32x4 acc[2][2];
#pragma unroll
    for (int i = 0; i < 2; i++)
#pragma unroll
        for (int j = 0; j < 2; j++) acc[i][j] = (f32x4){0.f, 0.f, 0.f, 0.f};

#pragma unroll
    for (int kk = 0; kk < KCAT / 32; ++kk) {
        const int ko = kk * 32;
        bf16x8 b0 = *reinterpret_cast<const bf16x8*>(bp + ko);
        bf16x8 b1 = *reinterpret_cast<const bf16x8*>(bp + (size_t)16 * KCAT + ko);
        const int bo = (kk * 64) ^ bx;              // kk*64 and hi*16 bits disjoint
#pragma unroll
        for (int rf = 0; rf < 2; ++rf) {
            bf16x8 a = *reinterpret_cast<const bf16x8*>(Ab + arow + rf * (16 * KCAT * 2) + bo);
            acc[rf][0] = __builtin_amdgcn_mfma_f32_16x16x32_bf16(a, b0, acc[rf][0], 0, 0, 0);
            acc[rf][1] = __builtin_amdgcn_mfma_f32_16x16x32_bf16(a, b1, acc[rf][1], 0, 0, 0);
        }
    }

    const int rq = (lane >> 4) * 4;
    if (MODE == 1) {
#pragma unroll
        for (int rf = 0; rf < 2; ++rf) {
#pragma unroll
            for (int cf = 0; cf < 2; ++cf) {
                const int col = col0 + cf * 16 + q;
#pragma unroll
                for (int r = 0; r < 4; ++r) {
                    const int row = m0 + rf * 16 + rq + r;
                    if (row < N_NODES) {
                        float v = fmaxf(acc[rf][cf][r] + bias[col], 0.f);
                        outb[(size_t)row * KCAT + 512 + col] = (short)f2bf(v);
                    }
                }
            }
        }
    } else {
        // fused global_add_pool: rows ascending per lane, batch sorted -> short runs
        const int colA = col0 + q, colB = col0 + 16 + q;
        int curb = -1;
        float run0 = 0.f, run1 = 0.f;
#pragma unroll
        for (int rf = 0; rf < 2; ++rf) {
#pragma unroll
            for (int r = 0; r < 4; ++r) {
                const int row = m0 + rf * 16 + rq + r;
                if (row < N_NODES) {
                    int b = batch[row];
                    if (b != curb) {
                        if (curb >= 0) {
                            atomicAdd(&g[curb * HID + colA], run0);
                            atomicAdd(&g[curb * HID + colB], run1);
                        }
                        curb = b; run0 = 0.f; run1 = 0.f;
                    }
                    run0 += acc[rf][0][r];
                    run1 += acc[rf][1][r];
                }
            }
        }
        if (curb >= 0) {
            atomicAdd(&g[curb * HID + colA], run0);
            atomicAdd(&g[curb * HID + colB], run1);
        }
    }
}

// per-graph: pooled = g + cnt*bias2; relu(pooled @ fc_w + fc_b) -> log_softmax
__global__ void k_fc(const float* __restrict__ g, const float* __restrict__ bias2,
                     const int* __restrict__ batch, const float* __restrict__ fcw,
                     const float* __restrict__ fcb, float* __restrict__ out) {
    __shared__ float pooled[HID];
    __shared__ float vals[N_CLS];
    __shared__ float s_lse;
    __shared__ int s_cnt;
    int gi = blockIdx.x, t = threadIdx.x;
    if (t == 0) {
        int lo = 0, hi = N_NODES;
        while (lo < hi) { int m = (lo + hi) >> 1; if (batch[m] < gi) lo = m + 1; else hi = m; }
        int lo2 = lo, hi2 = N_NODES;
        while (lo2 < hi2) { int m = (lo2 + hi2) >> 1; if (batch[m] < gi + 1) lo2 = m + 1; else hi2 = m; }
        s_cnt = lo2 - lo;
    }
    __syncthreads();
    pooled[t] = g[gi * HID + t] + (float)s_cnt * bias2[t];
    __syncthreads();
    if (t < N_CLS) {
        float acc = fcb[t];
        for (int k = 0; k < HID; k++) acc = fmaf(pooled[k], fcw[k * N_CLS + t], acc);
        vals[t] = fmaxf(acc, 0.f);
    }
    __syncthreads();
    if (t == 0) {
        float m = vals[0];
        for (int c = 1; c < N_CLS; c++) m = fmaxf(m, vals[c]);
        float ssum = 0.f;
        for (int c = 0; c < N_CLS; c++) ssum += expf(vals[c] - m);
        s_lse = m + logf(ssum);
    }
    __syncthreads();
    if (t < N_CLS) out[gi * N_CLS + t] = vals[t] - s_lse;
}

extern "C" void kernel_launch(void* const* d_in, const int* in_sizes, int n_in,
                              void* d_out, int out_size, void* d_ws, size_t ws_size,
                              hipStream_t stream) {
    const float* x      = (const float*)d_in[0];
    const int*   ei     = (const int*)d_in[1];
    const int*   src    = ei;
    const int*   dst    = ei + N_EDGES;
    const int*   et     = (const int*)d_in[2];
    const int*   batch  = (const int*)d_in[3];
    const float* basis1 = (const float*)d_in[4];
    const float* comp1  = (const float*)d_in[5];
    const float* root1  = (const float*)d_in[6];
    const float* bias1  = (const float*)d_in[7];
    const float* basis2 = (const float*)d_in[8];
    const float* comp2  = (const float*)d_in[9];
    const float* root2  = (const float*)d_in[10];
    const float* bias2  = (const float*)d_in[11];
    const float* fcw    = (const float*)d_in[12];
    const float* fcb    = (const float*)d_in[13];
    float* out = (float*)d_out;

    // workspace layout (~150 MB)
    short* CS   = (short*)d_ws;                        // [100032][640] bf16 = 128.04 MB
    short* Wt1  = CS + (size_t)N_ROWS * KCAT;          // [128][640] bf16
    short* Wt2  = Wt1 + HID * KCAT;                    // [128][640] bf16
    float* g    = (float*)(Wt2 + HID * KCAT);          // [512][128] f32
    int*   cnt  = (int*)(g + N_GRAPH * HID);           // SEG
    int*   off  = cnt + SEG;                           // SEG (padded offsets)
    int*   bsum = off + SEG;                           // 512
    int*   rank = bsum + 512;                          // E
    int*   ssrc = rank + N_EDGES;                      // SSRC_MAX (padded CSR)

    hipMemsetAsync(cnt, 0, SEG * sizeof(int), stream);
    hipMemsetAsync(g, 0, (size_t)N_GRAPH * HID * sizeof(float), stream);

    k_wt<FIN><<<(KCAT * HID + 255) / 256, 256, 0, stream>>>(basis1, comp1, root1, Wt1);
    k_wt<HID><<<(KCAT * HID + 255) / 256, 256, 0, stream>>>(basis2, comp2, root2, Wt2);
    k_xcvt<<<((N_NODES + 1) * HID + 255) / 256, 256, 0, stream>>>(x, CS);
    k_fill<<<(SSRC_MAX + 255) / 256, 256, 0, stream>>>(ssrc);

    // CSR build by (relation, dst): count(+rank) -> padded scan -> scatter
    k_count<<<(N_EDGES + 255) / 256, 256, 0, stream>>>(et, dst, cnt, rank);
    k_bsum<<<NB_SCAN, 256, 0, stream>>>(cnt, bsum);
    k_bpref<<<1, 64, 0, stream>>>(bsum, NB_SCAN);
    k_offsets<<<NB_SCAN, 256, 0, stream>>>(cnt, bsum, off);
    k_scatter<<<(N_EDGES + 255) / 256, 256, 0, stream>>>(et, src, dst, off, rank, ssrc);

    const int AGG_GRID  = N_NODES / 4;     // 1 wave/node, 4 waves/block
    const int GEMM_GRID = N_ROWS / BM;     // 3126

    // layer 1
    k_agg2<<<AGG_GRID, 256, 0, stream>>>(off, cnt, ssrc, CS);
    k_gemm<1><<<GEMM_GRID, 256, 0, stream>>>(CS, Wt1, bias1, CS, nullptr, nullptr);

    // layer 2 (pool fused into epilogue; bias2 folded into fc)
    k_agg2<<<AGG_GRID, 256, 0, stream>>>(off, cnt, ssrc, CS);
    k_gemm<2><<<GEMM_GRID, 256, 0, stream>>>(CS, Wt2, nullptr, nullptr, batch, g);

    // fc + log_softmax (with bias2 * node-count fold)
    k_fc<<<N_GRAPH, HID, 0, stream>>>(g, bias2, batch, fcw, fcb, out);
}

// Round 7
// 390.718 us; speedup vs baseline: 7.7971x; 1.2733x over previous
//
#include <hip/hip_runtime.h>
#include <hip/hip_bf16.h>
#include <cstddef>
#include <cstdint>

#define N_NODES 100000
#define N_ROWS  100032            // padded to 32-row tiles
#define DUMMY   100000            // zeroed pad row in feature buffers
#define N_EDGES 1600000
#define N_REL   4
#define N_BASES 30
#define FIN     86
#define HID     128
#define N_CLS   18
#define N_GRAPH 512
#define KCAT    640               // 4 relation blocks + root block, 128 each
#define BM      32                // rows per fused block
#define NKK     (KCAT / 32)       // 20 K-steps

#define SEG (N_REL * N_NODES)                         // 400000 segments
#define SSRC_MAX (N_EDGES + 3 * SEG)                  // padded CSR worst case
#define SCAN_CHUNK 1024
#define NB_SCAN ((SEG + SCAN_CHUNK - 1) / SCAN_CHUNK) // 391

typedef __attribute__((ext_vector_type(8))) short bf16x8;
typedef __attribute__((ext_vector_type(4))) float f32x4;

__device__ inline float blo(unsigned int u) {
    union { unsigned int i; float f; } c; c.i = u << 16; return c.f;
}
__device__ inline float bhi(unsigned int u) {
    union { unsigned int i; float f; } c; c.i = u & 0xffff0000u; return c.f;
}
__device__ inline unsigned short f2bf(float f) {
    __hip_bfloat16 h = __float2bfloat16(f);
    return *reinterpret_cast<unsigned short*>(&h);
}
__device__ inline unsigned int pk2(float lo, float hi) {
    return (unsigned int)f2bf(lo) | ((unsigned int)f2bf(hi) << 16);
}
__device__ inline int pad4i(int x) { return (x + 3) & ~3; }

// Stacked transposed weights: Wt[n][s], s = r*128+k (r<4: sum_b comp*basis) or 512+k (root).
template <int KV>
__global__ void k_wt(const float* __restrict__ basis, const float* __restrict__ comp,
                     const float* __restrict__ root, short* __restrict__ Wt) {
    int id = blockIdx.x * 256 + threadIdx.x;
    if (id >= KCAT * HID) return;
    int n = id & 127, s = id >> 7;
    int k = s & 127, blk = s >> 7;
    float v = 0.f;
    if (k < KV) {
        if (blk < N_REL) {
#pragma unroll
            for (int b = 0; b < N_BASES; ++b)
                v += comp[blk * N_BASES + b] * basis[((size_t)b * KV + k) * HID + n];
        } else {
            v = root[k * HID + n];
        }
    }
    Wt[(size_t)n * KCAT + s] = (short)f2bf(v);
}

// x[N,86] f32 -> X0[N_ROWS][128] bf16 (zero pad rows/cols); zero H1 pad rows (incl DUMMY)
__global__ void k_xcvt(const float* __restrict__ x, short* __restrict__ X0,
                       short* __restrict__ H1) {
    int id = blockIdx.x * 256 + threadIdx.x;
    if (id >= N_ROWS * HID) return;
    int n = id >> 7, k = id & 127;
    float v = (n < N_NODES && k < FIN) ? x[n * FIN + k] : 0.f;
    X0[id] = (short)f2bf(v);
    if (n >= N_NODES) H1[id] = 0;
}

// prefill padded CSR with DUMMY
__global__ void k_fill(int* __restrict__ p) {
    int i = blockIdx.x * 256 + threadIdx.x;
    if (i < SSRC_MAX) p[i] = DUMMY;
}

// histogram + per-edge rank in one atomic pass
__global__ void k_count(const int* __restrict__ et, const int* __restrict__ dst,
                        int* __restrict__ cnt, int* __restrict__ rank) {
    int e = blockIdx.x * 256 + threadIdx.x;
    if (e >= N_EDGES) return;
    rank[e] = atomicAdd(cnt + et[e] * N_NODES + dst[e], 1);
}

// ---- scan of pad4(cnt[SEG]) -> off[SEG] ----
__global__ void k_bsum(const int* __restrict__ cnt, int* __restrict__ bsum) {
    __shared__ int red[256];
    int base = blockIdx.x * SCAN_CHUNK + threadIdx.x * 4;
    int s = 0;
#pragma unroll
    for (int j = 0; j < 4; j++) { int idx = base + j; if (idx < SEG) s += pad4i(cnt[idx]); }
    red[threadIdx.x] = s;
    __syncthreads();
    for (int w = 128; w > 0; w >>= 1) {
        if (threadIdx.x < w) red[threadIdx.x] += red[threadIdx.x + w];
        __syncthreads();
    }
    if (threadIdx.x == 0) bsum[blockIdx.x] = red[0];
}

// parallel single-block exclusive scan of bsum (NB_SCAN < 512)
__global__ void k_bpref(int* __restrict__ bsum, int nb) {
    __shared__ int s[512];
    int t = threadIdx.x;
    int v = (t < nb) ? bsum[t] : 0;
    s[t] = v;
    __syncthreads();
    for (int d = 1; d < 512; d <<= 1) {
        int add = (t >= d) ? s[t - d] : 0;
        __syncthreads();
        s[t] += add;
        __syncthreads();
    }
    if (t < nb) bsum[t] = s[t] - v;
}

__global__ void k_offsets(const int* __restrict__ cnt, const int* __restrict__ bpref,
                          int* __restrict__ off) {
    __shared__ int tp[256];
    int t = threadIdx.x;
    int base = blockIdx.x * SCAN_CHUNK + t * 4;
    int v[4], s = 0;
#pragma unroll
    for (int j = 0; j < 4; j++) { int idx = base + j; v[j] = (idx < SEG) ? pad4i(cnt[idx]) : 0; s += v[j]; }
    tp[t] = s;
    __syncthreads();
    if (t == 0) { int run = 0; for (int i = 0; i < 256; i++) { int x = tp[i]; tp[i] = run; run += x; } }
    __syncthreads();
    int p = bpref[blockIdx.x] + tp[t];
#pragma unroll
    for (int j = 0; j < 4; j++) { int idx = base + j; if (idx < SEG) off[idx] = p; p += v[j]; }
}

// atomic-free scatter using precomputed rank (pad slots keep DUMMY)
__global__ void k_scatter(const int* __restrict__ et, const int* __restrict__ srcI,
                          const int* __restrict__ dstI, const int* __restrict__ off,
                          const int* __restrict__ rank, int* __restrict__ ssrc) {
    int e = blockIdx.x * 256 + threadIdx.x;
    if (e >= N_EDGES) return;
    int seg = et[e] * N_NODES + dstI[e];
    ssrc[off[seg] + rank[e]] = srcI[e];
}

// ===== fused agg+GEMM: one 32-row M-tile per block, 512 thr (8 waves) =====
// LDS A-tile As[32][640] bf16, XOR-swizzled (byte ^ ((row&7)<<4)).
//  phase 1: stage root block (cols 512..639) from F rows m0.. (1 uint4/thread)
//  phase 2: 32 groups x 16 lanes gather per-(node,rel) means straight into LDS
//  phase 3: B (Wt slice, 16 cols/wave) in 80 VGPRs; 40 ds_read_b128 + 40 MFMA/wave
//  epilogue: MODE 1 relu(.+bias)->H; MODE 2 run-compressed pool atomics into g
template <int MODE>
__launch_bounds__(512, 4)
__global__ void k_fused(const short* __restrict__ F,
                        const int* __restrict__ off, const int* __restrict__ cnt,
                        const int* __restrict__ ssrc,
                        const short* __restrict__ Wt,
                        const float* __restrict__ bias,
                        short* __restrict__ H,
                        const int* __restrict__ batch, float* __restrict__ g) {
    __shared__ short As[BM * KCAT];                 // 40960 B
    char* Ab = reinterpret_cast<char*>(As);
    const int tid = threadIdx.x;
    const int m0 = blockIdx.x * BM;

    // ---- phase 1: root block cols [512,640)
    {
        const int row = tid >> 4, cu = tid & 15;
        uint4 v = *reinterpret_cast<const uint4*>(F + (size_t)(m0 + row) * HID + cu * 8);
        const int p = (row * 1280 + 1024 + cu * 16) ^ ((row & 7) << 4);
        *reinterpret_cast<uint4*>(Ab + p) = v;
    }

    // ---- phase 2: relation means cols [0,512)
    {
        const int G = tid >> 4, q = tid & 15;
        const int node = m0 + G;
        if (node < N_NODES) {
            const int pbase = G * 1280 + q * 16;
            const int swz = (G & 7) << 4;
            for (int r = 0; r < N_REL; ++r) {
                const int seg = r * N_NODES + node;
                const int o0 = off[seg], c = cnt[seg];
                float a[8];
#pragma unroll
                for (int j = 0; j < 8; ++j) a[j] = 0.f;
                const int4* sp = reinterpret_cast<const int4*>(ssrc + o0);
                const int nch = (c + 3) >> 2;
                for (int ch = 0; ch < nch; ++ch) {
                    int4 e4 = sp[ch];
                    uint4 v0 = *reinterpret_cast<const uint4*>(F + (size_t)e4.x * HID + q * 8);
                    uint4 v1 = *reinterpret_cast<const uint4*>(F + (size_t)e4.y * HID + q * 8);
                    uint4 v2 = *reinterpret_cast<const uint4*>(F + (size_t)e4.z * HID + q * 8);
                    uint4 v3 = *reinterpret_cast<const uint4*>(F + (size_t)e4.w * HID + q * 8);
                    a[0] += blo(v0.x) + blo(v1.x) + blo(v2.x) + blo(v3.x);
                    a[1] += bhi(v0.x) + bhi(v1.x) + bhi(v2.x) + bhi(v3.x);
                    a[2] += blo(v0.y) + blo(v1.y) + blo(v2.y) + blo(v3.y);
                    a[3] += bhi(v0.y) + bhi(v1.y) + bhi(v2.y) + bhi(v3.y);
                    a[4] += blo(v0.z) + blo(v1.z) + blo(v2.z) + blo(v3.z);
                    a[5] += bhi(v0.z) + bhi(v1.z) + bhi(v2.z) + bhi(v3.z);
                    a[6] += blo(v0.w) + blo(v1.w) + blo(v2.w) + blo(v3.w);
                    a[7] += bhi(v0.w) + bhi(v1.w) + bhi(v2.w) + bhi(v3.w);
                }
                const float inv = (c > 0) ? 1.f / (float)c : 0.f;
                uint4 w;
                w.x = pk2(a[0] * inv, a[1] * inv);
                w.y = pk2(a[2] * inv, a[3] * inv);
                w.z = pk2(a[4] * inv, a[5] * inv);
                w.w = pk2(a[6] * inv, a[7] * inv);
                *reinterpret_cast<uint4*>(Ab + ((pbase + r * 256) ^ swz)) = w;
            }
        }
    }
    __syncthreads();

    // ---- phase 3: B in registers, MFMA over K=640
    const int wave = tid >> 6, lane = tid & 63;
    const int q = lane & 15, hi = lane >> 4;
    const int col = wave * 16 + q;

    bf16x8 bfrag[NKK];
    {
        const short* bp = Wt + (size_t)col * KCAT + hi * 8;
#pragma unroll
        for (int kk = 0; kk < NKK; ++kk)
            bfrag[kk] = *reinterpret_cast<const bf16x8*>(bp + kk * 32);
    }

    f32x4 acc[2];
    acc[0] = (f32x4){0.f, 0.f, 0.f, 0.f};
    acc[1] = (f32x4){0.f, 0.f, 0.f, 0.f};
    const int arow = q * 1280;
    const int bx = (hi * 16) ^ ((q & 7) << 4);
#pragma unroll
    for (int kk = 0; kk < NKK; ++kk) {
        const int bo = (kk * 64) ^ bx;
#pragma unroll
        for (int rf = 0; rf < 2; ++rf) {
            bf16x8 a = *reinterpret_cast<const bf16x8*>(Ab + arow + rf * (16 * 1280) + bo);
            acc[rf] = __builtin_amdgcn_mfma_f32_16x16x32_bf16(a, bfrag[kk], acc[rf], 0, 0, 0);
        }
    }

    // ---- epilogue
    if (MODE == 1) {
        const float bc = bias[col];
#pragma unroll
        for (int rf = 0; rf < 2; ++rf) {
#pragma unroll
            for (int r = 0; r < 4; ++r) {
                const int row = m0 + rf * 16 + hi * 4 + r;
                if (row < N_NODES) {
                    float v = fmaxf(acc[rf][r] + bc, 0.f);
                    H[(size_t)row * HID + col] = (short)f2bf(v);
                }
            }
        }
    } else {
        int curb = -1;
        float run = 0.f;
#pragma unroll
        for (int rf = 0; rf < 2; ++rf) {
#pragma unroll
            for (int r = 0; r < 4; ++r) {
                const int row = m0 + rf * 16 + hi * 4 + r;
                if (row < N_NODES) {
                    int b = batch[row];
                    if (b != curb) {
                        if (curb >= 0) atomicAdd(&g[curb * HID + col], run);
                        curb = b; run = 0.f;
                    }
                    run += acc[rf][r];
                }
            }
        }
        if (curb >= 0) atomicAdd(&g[curb * HID + col], run);
    }
}

// per-graph: pooled = g + cnt*bias2; relu(pooled @ fc_w + fc_b) -> log_softmax
__global__ void k_fc(const float* __restrict__ g, const float* __restrict__ bias2,
                     const int* __restrict__ batch, const float* __restrict__ fcw,
                     const float* __restrict__ fcb, float* __restrict__ out) {
    __shared__ float pooled[HID];
    __shared__ float vals[N_CLS];
    __shared__ float s_lse;
    __shared__ int s_cnt;
    int gi = blockIdx.x, t = threadIdx.x;
    if (t == 0) {
        int lo = 0, hi = N_NODES;
        while (lo < hi) { int m = (lo + hi) >> 1; if (batch[m] < gi) lo = m + 1; else hi = m; }
        int lo2 = lo, hi2 = N_NODES;
        while (lo2 < hi2) { int m = (lo2 + hi2) >> 1; if (batch[m] < gi + 1) lo2 = m + 1; else hi2 = m; }
        s_cnt = lo2 - lo;
    }
    __syncthreads();
    pooled[t] = g[gi * HID + t] + (float)s_cnt * bias2[t];
    __syncthreads();
    if (t < N_CLS) {
        float acc = fcb[t];
        for (int k = 0; k < HID; k++) acc = fmaf(pooled[k], fcw[k * N_CLS + t], acc);
        vals[t] = fmaxf(acc, 0.f);
    }
    __syncthreads();
    if (t == 0) {
        float m = vals[0];
        for (int c = 1; c < N_CLS; c++) m = fmaxf(m, vals[c]);
        float ssum = 0.f;
        for (int c = 0; c < N_CLS; c++) ssum += expf(vals[c] - m);
        s_lse = m + logf(ssum);
    }
    __syncthreads();
    if (t < N_CLS) out[gi * N_CLS + t] = vals[t] - s_lse;
}

extern "C" void kernel_launch(void* const* d_in, const int* in_sizes, int n_in,
                              void* d_out, int out_size, void* d_ws, size_t ws_size,
                              hipStream_t stream) {
    const float* x      = (const float*)d_in[0];
    const int*   ei     = (const int*)d_in[1];
    const int*   src    = ei;
    const int*   dst    = ei + N_EDGES;
    const int*   et     = (const int*)d_in[2];
    const int*   batch  = (const int*)d_in[3];
    const float* basis1 = (const float*)d_in[4];
    const float* comp1  = (const float*)d_in[5];
    const float* root1  = (const float*)d_in[6];
    const float* bias1  = (const float*)d_in[7];
    const float* basis2 = (const float*)d_in[8];
    const float* comp2  = (const float*)d_in[9];
    const float* root2  = (const float*)d_in[10];
    const float* bias2  = (const float*)d_in[11];
    const float* fcw    = (const float*)d_in[12];
    const float* fcb    = (const float*)d_in[13];
    float* out = (float*)d_out;

    // workspace layout (~73 MB)
    short* X0   = (short*)d_ws;                        // [N_ROWS][128] bf16
    short* H1   = X0 + (size_t)N_ROWS * HID;           // [N_ROWS][128] bf16
    short* Wt1  = H1 + (size_t)N_ROWS * HID;           // [128][640] bf16
    short* Wt2  = Wt1 + HID * KCAT;                    // [128][640] bf16
    float* g    = (float*)(Wt2 + HID * KCAT);          // [512][128] f32
    int*   cnt  = (int*)(g + N_GRAPH * HID);           // SEG
    int*   off  = cnt + SEG;                           // SEG (padded offsets)
    int*   bsum = off + SEG;                           // 512
    int*   rank = bsum + 512;                          // E
    int*   ssrc = rank + N_EDGES;                      // SSRC_MAX (padded CSR)

    hipMemsetAsync(cnt, 0, SEG * sizeof(int), stream);
    hipMemsetAsync(g, 0, (size_t)N_GRAPH * HID * sizeof(float), stream);

    k_wt<FIN><<<(KCAT * HID + 255) / 256, 256, 0, stream>>>(basis1, comp1, root1, Wt1);
    k_wt<HID><<<(KCAT * HID + 255) / 256, 256, 0, stream>>>(basis2, comp2, root2, Wt2);
    k_xcvt<<<(N_ROWS * HID + 255) / 256, 256, 0, stream>>>(x, X0, H1);
    k_fill<<<(SSRC_MAX + 255) / 256, 256, 0, stream>>>(ssrc);

    // CSR build by (relation, dst): count(+rank) -> padded scan -> scatter
    k_count<<<(N_EDGES + 255) / 256, 256, 0, stream>>>(et, dst, cnt, rank);
    k_bsum<<<NB_SCAN, 256, 0, stream>>>(cnt, bsum);
    k_bpref<<<1, 512, 0, stream>>>(bsum, NB_SCAN);
    k_offsets<<<NB_SCAN, 256, 0, stream>>>(cnt, bsum, off);
    k_scatter<<<(N_EDGES + 255) / 256, 256, 0, stream>>>(et, src, dst, off, rank, ssrc);

    const int FUSED_GRID = N_ROWS / BM;    // 3126

    // layer 1: h1 = relu( [means(x)|x] @ W1stack + bias1 )
    k_fused<1><<<FUSED_GRID, 512, 0, stream>>>(X0, off, cnt, ssrc, Wt1, bias1, H1,
                                               nullptr, nullptr);
    // layer 2: pool( [means(h1)|h1] @ W2stack ) fused; bias2 folded into fc
    k_fused<2><<<FUSED_GRID, 512, 0, stream>>>(H1, off, cnt, ssrc, Wt2, nullptr, nullptr,
                                               batch, g);

    // fc + log_softmax (with bias2 * node-count fold)
    k_fc<<<N_GRAPH, HID, 0, stream>>>(g, bias2, batch, fcw, fcb, out);
}